// Round 3
// baseline (3076.785 us; speedup 1.0000x reference)
//
#include <hip/hip_runtime.h>
#include <hip/hip_bf16.h>

// ---------------------------------------------------------------- zero ----
__global__ void zero_f32(float* p, int n) {
    int i = blockIdx.x * blockDim.x + threadIdx.x;
    int stride = gridDim.x * blockDim.x;
    for (; i < n; i += stride) p[i] = 0.f;
}

// ---------------------------------------------------------- node_proj ----
// Pa[n,c]     = sum_d W_L0[c,d] * x_a[n,d]          (c<16, d<64)
// Pv[n,c,i]   = sum_d W_L1[c,d] * x_v[n,d,i]        (d<32)
// Pd[n,c,i,j] = sum_d W_L2[c,d] * x_d[n,d,i,j]      (d<16)
__global__ void node_proj(const float* __restrict__ xa, const float* __restrict__ xv,
                          const float* __restrict__ xd,
                          const float* __restrict__ WL0, const float* __restrict__ WL1,
                          const float* __restrict__ WL2,
                          float* __restrict__ Pa, float* __restrict__ Pv,
                          float* __restrict__ Pd, int N) {
    int t = blockIdx.x * blockDim.x + threadIdx.x;
    int total = N * 208;
    if (t >= total) return;
    int n = t / 208, s = t % 208;
    if (s < 16) {
        float acc = 0.f;
        const float* x = xa + n * 64;
        const float* w = WL0 + s * 64;
        for (int d = 0; d < 64; ++d) acc += w[d] * x[d];
        Pa[n * 16 + s] = acc;
    } else if (s < 64) {
        int idx = s - 16, c = idx / 3, i = idx % 3;
        float acc = 0.f;
        const float* w = WL1 + c * 32;
        for (int d = 0; d < 32; ++d) acc += w[d] * xv[(n * 32 + d) * 3 + i];
        Pv[n * 48 + idx] = acc;
    } else {
        int idx = s - 64, c = idx / 9, ij = idx % 9;
        float acc = 0.f;
        const float* w = WL2 + c * 16;
        for (int d = 0; d < 16; ++d) acc += w[d] * xd[(n * 16 + d) * 9 + ij];
        Pd[n * 144 + idx] = acc;
    }
}

// --------------------------------------------------------- edge kernel ----
// one wave (64 lanes) per edge, 4 waves per 256-thread block
__global__ __launch_bounds__(256) void edge_kernel(
    const float* __restrict__ r_ij,
    const float* __restrict__ Pa, const float* __restrict__ Pv, const float* __restrict__ Pd,
    const float* __restrict__ Wenc, const float* __restrict__ benc,
    const float* __restrict__ W000, const float* __restrict__ W110, const float* __restrict__ W220,
    const float* __restrict__ W011, const float* __restrict__ W101, const float* __restrict__ W121,
    const float* __restrict__ W211, const float* __restrict__ W111,
    const float* __restrict__ W022, const float* __restrict__ W202, const float* __restrict__ W112,
    const float* __restrict__ W222, const float* __restrict__ W212,
    const float* __restrict__ Wdir, const float* __restrict__ W1, const float* __restrict__ pb1,
    const float* __restrict__ W2, const float* __restrict__ pb2,
    const float* __restrict__ W3, const float* __restrict__ pb3,
    const int* __restrict__ src, const int* __restrict__ dst,
    float* __restrict__ acc_a, float* __restrict__ acc_v, float* __restrict__ acc_d, int E) {
    const int wid = threadIdx.x >> 6;
    const int lane = threadIdx.x & 63;
    const int e = blockIdx.x * 4 + wid;

    __shared__ float s_xa[4][16], s_xv[4][48], s_xd[4][144], s_rad[4][16];
    __shared__ float s_ya[4][48], s_yv[4][240], s_yd[4][720];
    __shared__ float s_psia[4][64], s_h1[4][128], s_h2[4][128];

    const bool act = (e < E);
    int snode = 0;
    float rx = 0.f, ry = 0.f, rz = 0.f;

    if (act) {
        int j = dst[e];
        snode = src[e];
        float vx = 7.f * r_ij[e * 3 + 0];
        float vy = 7.f * r_ij[e * 3 + 1];
        float vz = 7.f * r_ij[e * 3 + 2];
        float nn = sqrtf(vx * vx + vy * vy + vz * vz);
        float sc = tanhf(nn) / (nn + 1e-12f);
        rx = vx * sc; ry = vy * sc; rz = vz * sc;
        // cooperative gather of projected dst-node features
        for (int s = lane; s < 208; s += 64) {
            if (s < 16)       s_xa[wid][s]      = Pa[j * 16 + s];
            else if (s < 64)  s_xv[wid][s - 16] = Pv[j * 48 + (s - 16)];
            else              s_xd[wid][s - 64] = Pd[j * 144 + (s - 64)];
        }
        // radial encoding -> rad[16]
        if (lane < 16) {
            float d = nn * (1.f / 7.f);   // |r_ij|
            float x8 = 8.f * d;
            float acc = benc[lane];
            for (int m = 0; m < 8; ++m) {
                float t = x8 - (float)m;
                acc += __expf(-0.5f * t * t) * Wenc[lane * 8 + m];
            }
            s_rad[wid][lane] = acc;
        }
    }
    __syncthreads();

    if (act) {
        const float r3[3] = {rx, ry, rz};
        // --- scalar intermediates ya[3][16] : t0=y000 t1=y110 t2=y220
        if (lane < 48) {
            int t = lane >> 4, c = lane & 15;
            float rad = s_rad[wid][c];
            float v;
            if (t == 0) v = s_xa[wid][c] * rad;
            else if (t == 1) {
                const float* xv = &s_xv[wid][c * 3];
                v = rad * (xv[0] * rx + xv[1] * ry + xv[2] * rz);
            } else {
                const float* xd = &s_xd[wid][c * 9];
                float m0 = xd[0] * rx + xd[1] * ry + xd[2] * rz;
                float m1 = xd[3] * rx + xd[4] * ry + xd[5] * rz;
                float m2 = xd[6] * rx + xd[7] * ry + xd[8] * rz;
                v = rad * (m0 * rx + m1 * ry + m2 * rz);
            }
            s_ya[wid][t * 16 + c] = v;
        }
        // --- vector intermediates yv[5][16][3] : 011,101,121,211,111
        for (int f = lane; f < 240; f += 64) {
            int t = f / 48, rem = f % 48, c = rem / 3, i = rem % 3;
            float rad = s_rad[wid][c];
            const float* xv = &s_xv[wid][c * 3];
            const float* xd = &s_xd[wid][c * 9];
            float v;
            if (t == 0)      v = s_xa[wid][c] * rad * r3[i];
            else if (t == 1) v = xv[i] * rad;
            else if (t == 2) v = rad * (xv[0] * rx + xv[1] * ry + xv[2] * rz) * r3[i];
            else if (t == 3) v = rad * (xd[i * 3 + 0] * rx + xd[i * 3 + 1] * ry + xd[i * 3 + 2] * rz);
            else {
                int i1 = (i + 1) % 3, i2 = (i + 2) % 3;
                v = rad * (xv[i1] * r3[i2] - xv[i2] * r3[i1]);
            }
            s_yv[wid][f] = v;
        }
        // --- matrix intermediates yd[5][16][9] : 022,202,112,222,212
        for (int f = lane; f < 720; f += 64) {
            int t = f / 144, rem = f % 144, c = rem / 9, ij = rem % 9, i = ij / 3, jj = ij % 3;
            float rad = s_rad[wid][c];
            const float* xd = &s_xd[wid][c * 9];
            float v;
            if (t == 0)      v = s_xa[wid][c] * rad * r3[i] * r3[jj];
            else if (t == 1) v = xd[ij] * rad;
            else if (t == 2) v = s_xv[wid][c * 3 + i] * rad * r3[jj];
            else if (t == 3) v = rad * r3[jj] * (xd[i * 3 + 0] * rx + xd[i * 3 + 1] * ry + xd[i * 3 + 2] * rz);
            else {
                int i1 = (i + 1) % 3, i2 = (i + 2) % 3;
                v = rad * (xd[i1 * 3 + jj] * r3[i2] - xd[i2 * 3 + jj] * r3[i1]);
            }
            s_yd[wid][f] = v;
        }
    }
    __syncthreads();

    if (act) {
        // psi_a[o] (kept for MLP)
        {
            int o = lane;
            float acc = 0.f;
            const float* ya = s_ya[wid];
            for (int c = 0; c < 16; ++c) {
                acc += W000[o * 16 + c] * ya[c];
                acc += W110[o * 16 + c] * ya[16 + c];
                acc += W220[o * 16 + c] * ya[32 + c];
            }
            s_psia[wid][o] = acc;
        }
        // psi_v -> atomic scatter (no MLP on vector channel)
        for (int f = lane; f < 96; f += 64) {
            int ch = f / 3, i = f % 3;
            float acc = 0.f;
            const float* yv = s_yv[wid];
            for (int c = 0; c < 16; ++c) {
                acc += W011[ch * 16 + c] * yv[0 * 48 + c * 3 + i];
                acc += W101[ch * 16 + c] * yv[1 * 48 + c * 3 + i];
                acc += W121[ch * 16 + c] * yv[2 * 48 + c * 3 + i];
                acc += W211[ch * 16 + c] * yv[3 * 48 + c * 3 + i];
                acc += W111[ch * 16 + c] * yv[4 * 48 + c * 3 + i];
            }
            atomicAdd(&acc_v[snode * 96 + f], acc);
        }
        // psi_d -> atomic scatter
        for (int f = lane; f < 144; f += 64) {
            int ch = f / 9, ij = f % 9;
            float acc = 0.f;
            const float* yd = s_yd[wid];
            for (int c = 0; c < 16; ++c) {
                acc += W022[ch * 16 + c] * yd[0 * 144 + c * 9 + ij];
                acc += W202[ch * 16 + c] * yd[1 * 144 + c * 9 + ij];
                acc += W112[ch * 16 + c] * yd[2 * 144 + c * 9 + ij];
                acc += W222[ch * 16 + c] * yd[3 * 144 + c * 9 + ij];
                acc += W212[ch * 16 + c] * yd[4 * 144 + c * 9 + ij];
            }
            atomicAdd(&acc_d[snode * 144 + f], acc);
        }
    }
    __syncthreads();

    // MLP: h1 = lrelu(psi_a @ W1^T + b1)
    if (act) {
        for (int k = lane; k < 128; k += 64) {
            float acc = pb1[k];
            for (int o = 0; o < 64; ++o) acc += W1[k * 64 + o] * s_psia[wid][o];
            s_h1[wid][k] = acc >= 0.f ? acc : 0.1f * acc;
        }
    }
    __syncthreads();
    if (act) {
        for (int k = lane; k < 128; k += 64) {
            float acc = pb2[k];
            for (int o = 0; o < 128; ++o) acc += W2[k * 128 + o] * s_h1[wid][o];
            s_h2[wid][k] = acc >= 0.f ? acc : 0.1f * acc;
        }
    }
    __syncthreads();
    if (act) {
        int o = lane;
        float acc = s_psia[wid][o] + pb3[o];
        for (int o2 = 0; o2 < 64; ++o2) acc += Wdir[o * 64 + o2] * s_psia[wid][o2];
        for (int k = 0; k < 128; ++k) acc += W3[o * 128 + k] * s_h2[wid][k];
        atomicAdd(&acc_a[snode * 64 + o], acc);
    }
}

// ----------------------------------------------------------- finalize ----
__global__ void finalize(const float* __restrict__ acc, float* __restrict__ out, int n) {
    int i = blockIdx.x * blockDim.x + threadIdx.x;
    int stride = gridDim.x * blockDim.x;
    for (; i < n; i += stride) out[i] = 0.1f * acc[i];
}

// -------------------------------------------------------------- launch ----
extern "C" void kernel_launch(void* const* d_in, const int* in_sizes, int n_in,
                              void* d_out, int out_size, void* d_ws, size_t ws_size,
                              hipStream_t stream) {
    const float* r_ij = (const float*)d_in[0];
    const float* x_a  = (const float*)d_in[1];
    const float* x_v  = (const float*)d_in[2];
    const float* x_d  = (const float*)d_in[3];
    const float* W_L0 = (const float*)d_in[4];
    const float* W_L1 = (const float*)d_in[5];
    const float* W_L2 = (const float*)d_in[6];
    const float* W000 = (const float*)d_in[7];
    const float* W110 = (const float*)d_in[8];
    const float* W220 = (const float*)d_in[9];
    const float* W011 = (const float*)d_in[10];
    const float* W101 = (const float*)d_in[11];
    const float* W121 = (const float*)d_in[12];
    const float* W211 = (const float*)d_in[13];
    const float* W022 = (const float*)d_in[14];
    const float* W202 = (const float*)d_in[15];
    const float* W112 = (const float*)d_in[16];
    const float* W222 = (const float*)d_in[17];
    const float* W111 = (const float*)d_in[18];
    const float* W212 = (const float*)d_in[19];
    const float* Wenc = (const float*)d_in[20];
    const float* benc = (const float*)d_in[21];
    const float* Wdir = (const float*)d_in[22];
    const float* W1   = (const float*)d_in[23];
    const float* b1   = (const float*)d_in[24];
    const float* W2   = (const float*)d_in[25];
    const float* b2   = (const float*)d_in[26];
    const float* W3   = (const float*)d_in[27];
    const float* b3   = (const float*)d_in[28];
    const int* src   = (const int*)d_in[29];
    const int* dst   = (const int*)d_in[30];

    const int E = in_sizes[29];
    const int N = in_sizes[1] / 64;

    float* ws = (float*)d_ws;
    float* acc   = ws;                       // N*304 f32 (acc_a | acc_v | acc_d)
    float* acc_a = acc;
    float* acc_v = acc + (size_t)N * 64;
    float* acc_d = acc + (size_t)N * 160;
    float* Pa = acc + (size_t)N * 304;       // N*16
    float* Pv = Pa + (size_t)N * 16;         // N*48
    float* Pd = Pv + (size_t)N * 48;         // N*144

    const int accN = N * 304;
    zero_f32<<<2048, 256, 0, stream>>>(acc, accN);
    node_proj<<<(N * 208 + 255) / 256, 256, 0, stream>>>(x_a, x_v, x_d, W_L0, W_L1, W_L2,
                                                         Pa, Pv, Pd, N);
    edge_kernel<<<(E + 3) / 4, 256, 0, stream>>>(
        r_ij, Pa, Pv, Pd, Wenc, benc,
        W000, W110, W220, W011, W101, W121, W211, W111,
        W022, W202, W112, W222, W212,
        Wdir, W1, b1, W2, b2, W3, b3,
        src, dst, acc_a, acc_v, acc_d, E);
    finalize<<<2048, 256, 0, stream>>>(acc, (float*)d_out, accN);
}

// Round 4
// 1043.204 us; speedup vs baseline: 2.9494x; 2.9494x over previous
//
#include <hip/hip_runtime.h>
#include <hip/hip_bf16.h>

typedef __hip_bfloat16 bf16;
typedef __attribute__((ext_vector_type(8))) short bf16x8;
typedef __attribute__((ext_vector_type(4))) float f32x4;

__device__ __forceinline__ short f2bb(float x) {
    bf16 h = __float2bfloat16(x);
    return *reinterpret_cast<short*>(&h);
}

// ---------------------------------------------------------------- zero ----
__global__ void zero_f32(float* p, int n) {
    int i = blockIdx.x * blockDim.x + threadIdx.x;
    int stride = gridDim.x * blockDim.x;
    for (; i < n; i += stride) p[i] = 0.f;
}

// ------------------------------------------------------------- prep_wb ----
// convert MLP weights f32 -> bf16 into ws
__global__ void prep_wb(const float* __restrict__ W1, const float* __restrict__ W2,
                        const float* __restrict__ W3, const float* __restrict__ Wdir,
                        bf16* __restrict__ out) {
    int i = blockIdx.x * 256 + threadIdx.x;
    if (i < 8192)       out[i] = __float2bfloat16(W1[i]);
    else if (i < 24576) out[i] = __float2bfloat16(W2[i - 8192]);
    else if (i < 32768) out[i] = __float2bfloat16(W3[i - 24576]);
    else if (i < 36864) out[i] = __float2bfloat16(Wdir[i - 32768]);
}

// ---------------------------------------------------------- node_proj ----
__global__ void node_proj(const float* __restrict__ xa, const float* __restrict__ xv,
                          const float* __restrict__ xd,
                          const float* __restrict__ WL0, const float* __restrict__ WL1,
                          const float* __restrict__ WL2,
                          float* __restrict__ Pa, float* __restrict__ Pv,
                          float* __restrict__ Pd, int N) {
    int t = blockIdx.x * blockDim.x + threadIdx.x;
    int total = N * 208;
    if (t >= total) return;
    int n = t / 208, s = t % 208;
    if (s < 16) {
        float acc = 0.f;
        const float* x = xa + n * 64;
        const float* w = WL0 + s * 64;
        for (int d = 0; d < 64; ++d) acc += w[d] * x[d];
        Pa[n * 16 + s] = acc;
    } else if (s < 64) {
        int idx = s - 16, c = idx / 3, i = idx % 3;
        float acc = 0.f;
        const float* w = WL1 + c * 32;
        for (int d = 0; d < 32; ++d) acc += w[d] * xv[(n * 32 + d) * 3 + i];
        Pv[n * 48 + idx] = acc;
    } else {
        int idx = s - 64, c = idx / 9, ij = idx % 9;
        float acc = 0.f;
        const float* w = WL2 + c * 16;
        for (int d = 0; d < 16; ++d) acc += w[d] * xd[(n * 16 + d) * 9 + ij];
        Pd[n * 144 + idx] = acc;
    }
}

// ---------------------------------------------------------- edge_core ----
// 4 waves/block, 1 edge per wave per loop iteration; weights in LDS
// (transposed layouts for vectorized conflict-light reads); y in per-wave
// LDS scratch with layouts [i][tc] / [ij][tc] so contraction reads are b128.
__global__ __launch_bounds__(256) void edge_core(
    const float* __restrict__ r_ij,
    const float* __restrict__ Pa, const float* __restrict__ Pv, const float* __restrict__ Pd,
    const float* __restrict__ Wenc, const float* __restrict__ benc,
    const float* __restrict__ W000, const float* __restrict__ W110, const float* __restrict__ W220,
    const float* __restrict__ W011, const float* __restrict__ W101, const float* __restrict__ W121,
    const float* __restrict__ W211, const float* __restrict__ W111,
    const float* __restrict__ W022, const float* __restrict__ W202, const float* __restrict__ W112,
    const float* __restrict__ W222, const float* __restrict__ W212,
    const int* __restrict__ src, const int* __restrict__ dst,
    float* __restrict__ acc_v, float* __restrict__ acc_d,
    bf16* __restrict__ psia, int E)
{
    __shared__ __align__(16) float wta[64][52];   // [o][t*16+c], t:{000,110,220}
    __shared__ __align__(16) float wtv[32][84];   // [ch][t*16+c], t:{011,101,121,211,111}
    __shared__ __align__(16) float wtd[16][84];   // [ch][t*16+c], t:{022,202,112,222,212}
    __shared__ float wenc_s[16][8];
    __shared__ float benc_s[16];
    __shared__ __align__(16) float sP[4][208];    // xa16 | xv48 | xd144
    __shared__ float srad[4][16];
    __shared__ __align__(16) float sya[4][48];
    __shared__ __align__(16) float syv[4][3][84]; // [i][tc]
    __shared__ __align__(16) float syd[4][9][84]; // [ij][tc]

    const int tid = threadIdx.x;
    const int wid = tid >> 6, lane = tid & 63;

    // ---- stage weights (once per block)
    for (int idx = tid; idx < 64 * 48; idx += 256) {
        int o = idx / 48, tc = idx % 48, t = tc >> 4, c = tc & 15;
        const float* W = (t == 0) ? W000 : (t == 1) ? W110 : W220;
        wta[o][tc] = W[o * 16 + c];
    }
    for (int idx = tid; idx < 32 * 80; idx += 256) {
        int ch = idx / 80, tc = idx % 80, t = tc >> 4, c = tc & 15;
        const float* W = (t == 0) ? W011 : (t == 1) ? W101 : (t == 2) ? W121 : (t == 3) ? W211 : W111;
        wtv[ch][tc] = W[ch * 16 + c];
    }
    for (int idx = tid; idx < 16 * 80; idx += 256) {
        int ch = idx / 80, tc = idx % 80, t = tc >> 4, c = tc & 15;
        const float* W = (t == 0) ? W022 : (t == 1) ? W202 : (t == 2) ? W112 : (t == 3) ? W222 : W212;
        wtd[ch][tc] = W[ch * 16 + c];
    }
    if (tid < 128) wenc_s[tid >> 3][tid & 7] = Wenc[tid];
    if (tid < 16) benc_s[tid] = benc[tid];
    __syncthreads();   // the only block-wide barrier

    const int gw = blockIdx.x * 4 + wid;
    const int nw = gridDim.x * 4;
    for (int e = gw; e < E; e += nw) {
        int j  = dst[e];
        int sn = src[e];
        float vx = 7.f * r_ij[e * 3 + 0];
        float vy = 7.f * r_ij[e * 3 + 1];
        float vz = 7.f * r_ij[e * 3 + 2];
        float nn = sqrtf(vx * vx + vy * vy + vz * vz);
        float sc = tanhf(nn) / (nn + 1e-12f);
        float rx = vx * sc, ry = vy * sc, rz = vz * sc;
        const float r3[3] = {rx, ry, rz};

        // gather projected dst-node features (wave-private scratch, no barrier)
        if (lane < 16) sP[wid][lane] = Pa[j * 16 + lane];
        if (lane < 48) sP[wid][16 + lane] = Pv[j * 48 + lane];
        for (int s = lane; s < 144; s += 64) sP[wid][64 + s] = Pd[j * 144 + s];
        if (lane < 16) {
            float x8 = nn * (8.f / 7.f);
            float a = benc_s[lane];
            #pragma unroll
            for (int m = 0; m < 8; ++m) {
                float t = x8 - (float)m;
                a += __expf(-0.5f * t * t) * wenc_s[lane][m];
            }
            srad[wid][lane] = a;
        }

        // ---- build ya (48)
        if (lane < 48) {
            int t = lane >> 4, c = lane & 15;
            float rad = srad[wid][c];
            float v;
            if (t == 0) v = sP[wid][c] * rad;
            else if (t == 1) {
                const float* xv = &sP[wid][16 + c * 3];
                v = rad * (xv[0] * rx + xv[1] * ry + xv[2] * rz);
            } else {
                const float* xd = &sP[wid][64 + c * 9];
                float m0 = xd[0] * rx + xd[1] * ry + xd[2] * rz;
                float m1 = xd[3] * rx + xd[4] * ry + xd[5] * rz;
                float m2 = xd[6] * rx + xd[7] * ry + xd[8] * rz;
                v = rad * (m0 * rx + m1 * ry + m2 * rz);
            }
            sya[wid][lane] = v;
        }
        // ---- build yv (240): f = tc*3 + i
        for (int f = lane; f < 240; f += 64) {
            int tc = f / 3, i = f % 3;
            int t = tc >> 4, c = tc & 15;
            float rad = srad[wid][c];
            const float* xv = &sP[wid][16 + c * 3];
            const float* xd = &sP[wid][64 + c * 9];
            float v;
            if (t == 0)      v = sP[wid][c] * rad * r3[i];
            else if (t == 1) v = xv[i] * rad;
            else if (t == 2) v = rad * (xv[0] * rx + xv[1] * ry + xv[2] * rz) * r3[i];
            else if (t == 3) v = rad * (xd[i * 3 + 0] * rx + xd[i * 3 + 1] * ry + xd[i * 3 + 2] * rz);
            else {
                int i1 = (i + 1) % 3, i2 = (i + 2) % 3;
                v = rad * (xv[i1] * r3[i2] - xv[i2] * r3[i1]);
            }
            syv[wid][i][tc] = v;
        }
        // ---- build yd (720): f = tc*9 + ij
        for (int f = lane; f < 720; f += 64) {
            int tc = f / 9, ij = f % 9;
            int t = tc >> 4, c = tc & 15;
            int i = ij / 3, jj = ij % 3;
            float rad = srad[wid][c];
            const float* xd = &sP[wid][64 + c * 9];
            float v;
            if (t == 0)      v = sP[wid][c] * rad * r3[i] * r3[jj];
            else if (t == 1) v = xd[ij] * rad;
            else if (t == 2) v = sP[wid][16 + c * 3 + i] * rad * r3[jj];
            else if (t == 3) v = rad * r3[jj] * (xd[i * 3 + 0] * rx + xd[i * 3 + 1] * ry + xd[i * 3 + 2] * rz);
            else {
                int i1 = (i + 1) % 3, i2 = (i + 2) % 3;
                v = rad * (xd[i1 * 3 + jj] * r3[i2] - xd[i2 * 3 + jj] * r3[i1]);
            }
            syd[wid][ij][tc] = v;
        }

        // ---- psi_a (lane = o), write bf16 for MLP kernel
        {
            float a = 0.f;
            const f32x4* w = (const f32x4*)&wta[lane][0];
            const f32x4* y = (const f32x4*)&sya[wid][0];
            #pragma unroll
            for (int g = 0; g < 12; ++g) {
                f32x4 wv = w[g], yv4 = y[g];
                a += wv.x * yv4.x + wv.y * yv4.y + wv.z * yv4.z + wv.w * yv4.w;
            }
            psia[(size_t)e * 64 + lane] = __float2bfloat16(a);
        }
        // ---- psi_v (96 outputs, 2 passes) -> atomic scatter
        #pragma unroll
        for (int p = 0; p < 2; ++p) {
            int f = p * 64 + lane;
            if (f < 96) {
                int ch = f / 3, i = f % 3;
                float a = 0.f;
                const f32x4* w = (const f32x4*)&wtv[ch][0];
                const f32x4* y = (const f32x4*)&syv[wid][i][0];
                #pragma unroll
                for (int g = 0; g < 20; ++g) {
                    f32x4 wv = w[g], yv4 = y[g];
                    a += wv.x * yv4.x + wv.y * yv4.y + wv.z * yv4.z + wv.w * yv4.w;
                }
                atomicAdd(&acc_v[(size_t)sn * 96 + f], a);
            }
        }
        // ---- psi_d (144 outputs, 3 passes) -> atomic scatter
        #pragma unroll
        for (int p = 0; p < 3; ++p) {
            int f = p * 64 + lane;
            if (f < 144) {
                int ch = f / 9, ij = f % 9;
                float a = 0.f;
                const f32x4* w = (const f32x4*)&wtd[ch][0];
                const f32x4* y = (const f32x4*)&syd[wid][ij][0];
                #pragma unroll
                for (int g = 0; g < 20; ++g) {
                    f32x4 wv = w[g], yv4 = y[g];
                    a += wv.x * yv4.x + wv.y * yv4.y + wv.z * yv4.z + wv.w * yv4.w;
                }
                atomicAdd(&acc_d[(size_t)sn * 144 + f], a);
            }
        }
    }
}

// --------------------------------------------------------- mlp_kernel ----
// 32-edge tile per block, 4 waves. MFMA bf16 16x16x32.
// layer1: h1 = lrelu(X@W1^T+b1)   (wave -> 32 of 128 cols)
// layer2: h2 = lrelu(h1@W2^T+b2)  (wave -> 32 of 128 cols)
// layer3: out = X + X@Wdir^T + h2@W3^T + b3 (wave -> 16 of 64 cols) -> atomic scatter
__global__ __launch_bounds__(256) void mlp_kernel(
    const bf16* __restrict__ psia,
    const bf16* __restrict__ Wb1, const bf16* __restrict__ Wb2,
    const bf16* __restrict__ Wb3, const bf16* __restrict__ Wbdir,
    const float* __restrict__ b1, const float* __restrict__ b2, const float* __restrict__ b3,
    const int* __restrict__ src, float* __restrict__ acc_a, int E)
{
    const int tid = threadIdx.x;
    const int wid = tid >> 6, lane = tid & 63;
    const int q = lane >> 4, r16 = lane & 15;
    const int e0 = blockIdx.x * 32;

    __shared__ __align__(16) short h1[32][128];  // bf16 bits, chunk-XOR swizzled
    __shared__ __align__(16) short h2[32][128];

    // ---------- layer 1
    f32x4 acc1[2][2] = {};
    #pragma unroll
    for (int ks = 0; ks < 2; ++ks) {
        bf16x8 bfr[2];
        #pragma unroll
        for (int n = 0; n < 2; ++n) {
            int col = wid * 32 + n * 16 + r16;
            bfr[n] = *(const bf16x8*)((const short*)Wb1 + col * 64 + ks * 32 + q * 8);
        }
        #pragma unroll
        for (int m = 0; m < 2; ++m) {
            int row = e0 + m * 16 + r16;
            bf16x8 afr = *(const bf16x8*)((const short*)psia + (size_t)row * 64 + ks * 32 + q * 8);
            #pragma unroll
            for (int n = 0; n < 2; ++n)
                acc1[m][n] = __builtin_amdgcn_mfma_f32_16x16x32_bf16(afr, bfr[n], acc1[m][n], 0, 0, 0);
        }
    }
    #pragma unroll
    for (int m = 0; m < 2; ++m)
        #pragma unroll
        for (int n = 0; n < 2; ++n) {
            int col = wid * 32 + n * 16 + r16;
            float bias = b1[col];
            #pragma unroll
            for (int jj = 0; jj < 4; ++jj) {
                int row = m * 16 + q * 4 + jj;
                float v = acc1[m][n][jj] + bias;
                v = v >= 0.f ? v : 0.1f * v;
                int chunk = (col >> 3) ^ (row & 7);
                h1[row][(chunk << 3) | (col & 7)] = f2bb(v);
            }
        }
    __syncthreads();

    // ---------- layer 2
    f32x4 acc2[2][2] = {};
    #pragma unroll
    for (int ks = 0; ks < 4; ++ks) {
        bf16x8 bfr[2];
        #pragma unroll
        for (int n = 0; n < 2; ++n) {
            int col = wid * 32 + n * 16 + r16;
            bfr[n] = *(const bf16x8*)((const short*)Wb2 + col * 128 + ks * 32 + q * 8);
        }
        #pragma unroll
        for (int m = 0; m < 2; ++m) {
            int row = m * 16 + r16;
            int chunk = (q + ks * 4) ^ (row & 7);
            bf16x8 afr = *(const bf16x8*)&h1[row][chunk << 3];
            #pragma unroll
            for (int n = 0; n < 2; ++n)
                acc2[m][n] = __builtin_amdgcn_mfma_f32_16x16x32_bf16(afr, bfr[n], acc2[m][n], 0, 0, 0);
        }
    }
    __syncthreads();   // all h1 reads done before h2 writes begin (reuse-safe)
    #pragma unroll
    for (int m = 0; m < 2; ++m)
        #pragma unroll
        for (int n = 0; n < 2; ++n) {
            int col = wid * 32 + n * 16 + r16;
            float bias = b2[col];
            #pragma unroll
            for (int jj = 0; jj < 4; ++jj) {
                int row = m * 16 + q * 4 + jj;
                float v = acc2[m][n][jj] + bias;
                v = v >= 0.f ? v : 0.1f * v;
                int chunk = (col >> 3) ^ (row & 7);
                h2[row][(chunk << 3) | (col & 7)] = f2bb(v);
            }
        }
    __syncthreads();

    // ---------- layer 3 + direct + residual
    f32x4 acc3[2] = {};
    int col3 = wid * 16 + r16;
    #pragma unroll
    for (int ks = 0; ks < 4; ++ks) {
        bf16x8 bfr = *(const bf16x8*)((const short*)Wb3 + col3 * 128 + ks * 32 + q * 8);
        #pragma unroll
        for (int m = 0; m < 2; ++m) {
            int row = m * 16 + r16;
            int chunk = (q + ks * 4) ^ (row & 7);
            bf16x8 afr = *(const bf16x8*)&h2[row][chunk << 3];
            acc3[m] = __builtin_amdgcn_mfma_f32_16x16x32_bf16(afr, bfr, acc3[m], 0, 0, 0);
        }
    }
    #pragma unroll
    for (int ks = 0; ks < 2; ++ks) {
        bf16x8 bfr = *(const bf16x8*)((const short*)Wbdir + col3 * 64 + ks * 32 + q * 8);
        #pragma unroll
        for (int m = 0; m < 2; ++m) {
            int row = e0 + m * 16 + r16;
            bf16x8 afr = *(const bf16x8*)((const short*)psia + (size_t)row * 64 + ks * 32 + q * 8);
            acc3[m] = __builtin_amdgcn_mfma_f32_16x16x32_bf16(afr, bfr, acc3[m], 0, 0, 0);
        }
    }
    float b3v = b3[col3];
    #pragma unroll
    for (int m = 0; m < 2; ++m)
        #pragma unroll
        for (int jj = 0; jj < 4; ++jj) {
            int rloc = m * 16 + q * 4 + jj;
            int e = e0 + rloc;
            if (e < E) {
                float xv = __bfloat162float(psia[(size_t)e * 64 + col3]);
                float v = acc3[m][jj] + xv + b3v;
                atomicAdd(&acc_a[(size_t)src[e] * 64 + col3], v);
            }
        }
}

// ----------------------------------------------------------- finalize ----
__global__ void finalize(const float* __restrict__ acc, float* __restrict__ out, int n) {
    int i = blockIdx.x * blockDim.x + threadIdx.x;
    int stride = gridDim.x * blockDim.x;
    for (; i < n; i += stride) out[i] = 0.1f * acc[i];
}

// -------------------------------------------------------------- launch ----
extern "C" void kernel_launch(void* const* d_in, const int* in_sizes, int n_in,
                              void* d_out, int out_size, void* d_ws, size_t ws_size,
                              hipStream_t stream) {
    const float* r_ij = (const float*)d_in[0];
    const float* x_a  = (const float*)d_in[1];
    const float* x_v  = (const float*)d_in[2];
    const float* x_d  = (const float*)d_in[3];
    const float* W_L0 = (const float*)d_in[4];
    const float* W_L1 = (const float*)d_in[5];
    const float* W_L2 = (const float*)d_in[6];
    const float* W000 = (const float*)d_in[7];
    const float* W110 = (const float*)d_in[8];
    const float* W220 = (const float*)d_in[9];
    const float* W011 = (const float*)d_in[10];
    const float* W101 = (const float*)d_in[11];
    const float* W121 = (const float*)d_in[12];
    const float* W211 = (const float*)d_in[13];
    const float* W022 = (const float*)d_in[14];
    const float* W202 = (const float*)d_in[15];
    const float* W112 = (const float*)d_in[16];
    const float* W222 = (const float*)d_in[17];
    const float* W111 = (const float*)d_in[18];
    const float* W212 = (const float*)d_in[19];
    const float* Wenc = (const float*)d_in[20];
    const float* benc = (const float*)d_in[21];
    const float* Wdir = (const float*)d_in[22];
    const float* W1   = (const float*)d_in[23];
    const float* b1   = (const float*)d_in[24];
    const float* W2   = (const float*)d_in[25];
    const float* b2   = (const float*)d_in[26];
    const float* W3   = (const float*)d_in[27];
    const float* b3   = (const float*)d_in[28];
    const int* src    = (const int*)d_in[29];
    const int* dst    = (const int*)d_in[30];

    const int E = in_sizes[29];
    const int N = in_sizes[1] / 64;

    // ws layout
    float* acc   = (float*)d_ws;                       // N*304 f32
    float* acc_a = acc;
    float* acc_v = acc + (size_t)N * 64;
    float* acc_d = acc + (size_t)N * 160;
    float* Pa    = acc + (size_t)N * 304;              // N*16
    float* Pv    = Pa + (size_t)N * 16;                // N*48
    float* Pd    = Pv + (size_t)N * 48;                // N*144
    bf16*  psia  = (bf16*)(Pd + (size_t)N * 144);      // E*64 bf16
    bf16*  Wb    = (bf16*)((char*)psia + (size_t)E * 64 * 2);
    bf16*  Wb1   = Wb;                                 // 8192
    bf16*  Wb2   = Wb + 8192;                          // 16384
    bf16*  Wb3   = Wb + 24576;                         // 8192
    bf16*  Wbdir = Wb + 32768;                         // 4096

    const int accN = N * 304;
    zero_f32<<<2048, 256, 0, stream>>>(acc, accN);
    prep_wb<<<144, 256, 0, stream>>>(W1, W2, W3, Wdir, Wb);
    node_proj<<<(N * 208 + 255) / 256, 256, 0, stream>>>(x_a, x_v, x_d, W_L0, W_L1, W_L2,
                                                         Pa, Pv, Pd, N);
    edge_core<<<768, 256, 0, stream>>>(
        r_ij, Pa, Pv, Pd, Wenc, benc,
        W000, W110, W220, W011, W101, W121, W211, W111,
        W022, W202, W112, W222, W212,
        src, dst, acc_v, acc_d, psia, E);
    mlp_kernel<<<(E + 31) / 32, 256, 0, stream>>>(
        psia, Wb1, Wb2, Wb3, Wbdir, b1, b2, b3, src, acc_a, E);
    finalize<<<2048, 256, 0, stream>>>(acc, (float*)d_out, accN);
}

// Round 5
// 658.529 us; speedup vs baseline: 4.6722x; 1.5841x over previous
//
#include <hip/hip_runtime.h>
#include <hip/hip_bf16.h>

typedef __hip_bfloat16 bf16;
typedef __attribute__((ext_vector_type(8))) short bf16x8;
typedef __attribute__((ext_vector_type(4))) float f32x4;

__device__ __forceinline__ short f2bb(float x) {
    bf16 h = __float2bfloat16(x);
    return *reinterpret_cast<short*>(&h);
}
__device__ __forceinline__ float bb2f(short s) {
    bf16 h = *reinterpret_cast<bf16*>(&s);
    return __bfloat162float(h);
}

// ---------------------------------------------------------------- zero ----
__global__ void zero_f32(float* p, int n) {
    int i = blockIdx.x * blockDim.x + threadIdx.x;
    int stride = gridDim.x * blockDim.x;
    for (; i < n; i += stride) p[i] = 0.f;
}

// -------------------------------------------------------------- prep_w ----
// pack all GEMM weights as bf16 [out][k] with K zero-padded:
//  Wa  [64][64]   (k = t*16+c, t:{000,110,220}, cols 48..63 = 0)   [0, 4096)
//  Wv  [32][96]   (t:{011,101,121,211,111}, cols 80..95 = 0)       [4096, 7168)
//  Wd  [16][96]   (t:{022,202,112,222,212}, cols 80..95 = 0)       [7168, 8704)
//  Wb1 [128][64]                                                   [8704, 16896)
//  Wb2 [128][128]                                                  [16896, 33280)
//  Wb3 [64][128]                                                   [33280, 41472)
//  Wbdir [64][64]                                                  [41472, 45568)
__global__ void prep_w(
    const float* __restrict__ W000, const float* __restrict__ W110, const float* __restrict__ W220,
    const float* __restrict__ W011, const float* __restrict__ W101, const float* __restrict__ W121,
    const float* __restrict__ W211, const float* __restrict__ W111,
    const float* __restrict__ W022, const float* __restrict__ W202, const float* __restrict__ W112,
    const float* __restrict__ W222, const float* __restrict__ W212,
    const float* __restrict__ W1, const float* __restrict__ W2, const float* __restrict__ W3,
    const float* __restrict__ Wdir, bf16* __restrict__ out) {
    int i = blockIdx.x * 256 + threadIdx.x;
    if (i >= 45568) return;
    float v = 0.f;
    if (i < 4096) {
        int o = i >> 6, k = i & 63;
        if (k < 48) {
            int t = k >> 4, c = k & 15;
            const float* W = (t == 0) ? W000 : (t == 1) ? W110 : W220;
            v = W[o * 16 + c];
        }
    } else if (i < 7168) {
        int r = i - 4096, ch = r / 96, k = r % 96;
        if (k < 80) {
            int t = k >> 4, c = k & 15;
            const float* W = (t == 0) ? W011 : (t == 1) ? W101 : (t == 2) ? W121 : (t == 3) ? W211 : W111;
            v = W[ch * 16 + c];
        }
    } else if (i < 8704) {
        int r = i - 7168, ch = r / 96, k = r % 96;
        if (k < 80) {
            int t = k >> 4, c = k & 15;
            const float* W = (t == 0) ? W022 : (t == 1) ? W202 : (t == 2) ? W112 : (t == 3) ? W222 : W212;
            v = W[ch * 16 + c];
        }
    } else if (i < 16896) v = W1[i - 8704];
    else if (i < 33280) v = W2[i - 16896];
    else if (i < 41472) v = W3[i - 33280];
    else v = Wdir[i - 41472];
    out[i] = __float2bfloat16(v);
}

// ---------------------------------------------------------- node_proj ----
__global__ void node_proj(const float* __restrict__ xa, const float* __restrict__ xv,
                          const float* __restrict__ xd,
                          const float* __restrict__ WL0, const float* __restrict__ WL1,
                          const float* __restrict__ WL2,
                          float* __restrict__ Pa, float* __restrict__ Pv,
                          float* __restrict__ Pd, int N) {
    int t = blockIdx.x * blockDim.x + threadIdx.x;
    int total = N * 208;
    if (t >= total) return;
    int n = t / 208, s = t % 208;
    if (s < 16) {
        float acc = 0.f;
        const float* x = xa + n * 64;
        const float* w = WL0 + s * 64;
        for (int d = 0; d < 64; ++d) acc += w[d] * x[d];
        Pa[n * 16 + s] = acc;
    } else if (s < 64) {
        int idx = s - 16, c = idx / 3, i = idx % 3;
        float acc = 0.f;
        const float* w = WL1 + c * 32;
        for (int d = 0; d < 32; ++d) acc += w[d] * xv[(n * 32 + d) * 3 + i];
        Pv[n * 48 + idx] = acc;
    } else {
        int idx = s - 64, c = idx / 9, ij = idx % 9;
        float acc = 0.f;
        const float* w = WL2 + c * 16;
        for (int d = 0; d < 16; ++d) acc += w[d] * xd[(n * 16 + d) * 9 + ij];
        Pd[n * 144 + idx] = acc;
    }
}

// ---------------------------------------------------------- edge_mfma ----
// 16 edges per block (256 threads, 4 waves). Phases:
//  1. y-build: thread (le, c) computes all 63 y values for (edge le, channel c),
//     writes bf16 into MFMA-A-layout LDS (row stride 104 bf16 -> 2-way banks).
//  2. tensor GEMMs on MFMA (wave0: psi_a; wave1: psi_v; waves2/3: psi_d),
//     weights as B-frags straight from global bf16 (L1-hot).
//  3. psi_v / psi_d -> atomicAdd scatter; psi_a -> LDS -> fused MLP (all waves)
//     -> atomicAdd scatter.
__global__ __launch_bounds__(256) void edge_mfma(
    const float* __restrict__ r_ij,
    const float* __restrict__ Pa, const float* __restrict__ Pv, const float* __restrict__ Pd,
    const float* __restrict__ Wenc, const float* __restrict__ benc,
    const bf16* __restrict__ Wa, const bf16* __restrict__ Wv, const bf16* __restrict__ Wd,
    const bf16* __restrict__ Wb1, const bf16* __restrict__ Wb2,
    const bf16* __restrict__ Wb3, const bf16* __restrict__ Wbdir,
    const float* __restrict__ b1, const float* __restrict__ b2, const float* __restrict__ b3,
    const int* __restrict__ src, const int* __restrict__ dst,
    float* __restrict__ acc_a, float* __restrict__ acc_v, float* __restrict__ acc_d, int E)
{
    __shared__ __align__(16) char smem[42304];
    short* SYA   = (short*)smem;            // [16][72]  psi_a A-operand (K=64 used)
    short* SYV   = (short*)(smem + 2304);   // [48][104] psi_v A (K=96, 80 real)
    short* SYD   = (short*)(smem + 12288);  // [144][104] psi_d A
    short* SPSIA = SYV;                     // [16][72]  psi_a result (aliases SYV)
    short* SH1   = (short*)(smem + 4608);   // [16][136] (aliases SYV tail)
    short* SH2   = SYD;                     // [16][136] (aliases SYD head)
    int*   SSRC  = (int*)(smem + 42240);    // [16]

    const int tid = threadIdx.x;
    const int e0 = blockIdx.x * 16;

    // ---- zero K-pad columns
    {
        int x = tid;
        if (x < 256) SYA[(x >> 4) * 72 + 48 + (x & 15)] = 0;
        for (int y = tid; y < 768; y += 256)  SYV[(y / 16) * 104 + 80 + (y & 15)] = 0;
        for (int y = tid; y < 2304; y += 256) SYD[(y / 16) * 104 + 80 + (y & 15)] = 0;
    }

    // ---- phase 1: y-build. thread = (local edge le, channel c)
    {
        const int le = tid >> 4, c = tid & 15;
        const int e = e0 + le;
        if (e < E) {
            const int j = dst[e];
            if (c == 0) SSRC[le] = src[e];
            float vx = 7.f * r_ij[e * 3 + 0];
            float vy = 7.f * r_ij[e * 3 + 1];
            float vz = 7.f * r_ij[e * 3 + 2];
            float nn = sqrtf(vx * vx + vy * vy + vz * vz);
            float sc = tanhf(nn) / (nn + 1e-12f);
            float rr[3] = {vx * sc, vy * sc, vz * sc};
            float x8 = nn * (8.f / 7.f);
            float rad = benc[c];
            #pragma unroll
            for (int m = 0; m < 8; ++m) {
                float tt = x8 - (float)m;
                rad += __expf(-0.5f * tt * tt) * Wenc[c * 8 + m];
            }
            float xa = Pa[j * 16 + c];
            float xv[3], xd[9];
            #pragma unroll
            for (int i = 0; i < 3; ++i) xv[i] = Pv[j * 48 + c * 3 + i];
            #pragma unroll
            for (int k = 0; k < 9; ++k) xd[k] = Pd[j * 144 + c * 9 + k];
            float dotv = xv[0] * rr[0] + xv[1] * rr[1] + xv[2] * rr[2];
            float mv[3];
            #pragma unroll
            for (int i = 0; i < 3; ++i)
                mv[i] = xd[i * 3] * rr[0] + xd[i * 3 + 1] * rr[1] + xd[i * 3 + 2] * rr[2];
            float quad = mv[0] * rr[0] + mv[1] * rr[1] + mv[2] * rr[2];
            // ya: t order {000,110,220}
            SYA[le * 72 + c]      = f2bb(xa * rad);
            SYA[le * 72 + 16 + c] = f2bb(rad * dotv);
            SYA[le * 72 + 32 + c] = f2bb(rad * quad);
            // yv rows (le*3+i), t order {011,101,121,211,111}
            #pragma unroll
            for (int i = 0; i < 3; ++i) {
                int row = (le * 3 + i) * 104;
                int i1 = (i + 1) % 3, i2 = (i + 2) % 3;
                SYV[row + c]      = f2bb(xa * rad * rr[i]);
                SYV[row + 16 + c] = f2bb(rad * xv[i]);
                SYV[row + 32 + c] = f2bb(rad * dotv * rr[i]);
                SYV[row + 48 + c] = f2bb(rad * mv[i]);
                SYV[row + 64 + c] = f2bb(rad * (xv[i1] * rr[i2] - xv[i2] * rr[i1]));
            }
            // yd rows (le*9+i*3+jj), t order {022,202,112,222,212}
            #pragma unroll
            for (int i = 0; i < 3; ++i) {
                int i1 = (i + 1) % 3, i2 = (i + 2) % 3;
                #pragma unroll
                for (int jj = 0; jj < 3; ++jj) {
                    int row = (le * 9 + i * 3 + jj) * 104;
                    SYD[row + c]      = f2bb(xa * rad * rr[i] * rr[jj]);
                    SYD[row + 16 + c] = f2bb(rad * xd[i * 3 + jj]);
                    SYD[row + 32 + c] = f2bb(rad * xv[i] * rr[jj]);
                    SYD[row + 48 + c] = f2bb(rad * mv[i] * rr[jj]);
                    SYD[row + 64 + c] = f2bb(rad * (xd[i1 * 3 + jj] * rr[i2] - xd[i2 * 3 + jj] * rr[i1]));
                }
            }
        } else if (c == 0) SSRC[le] = 0;
    }
    __syncthreads();   // b1: y ready

    // ---- phase 2: tensor GEMMs (per-wave roles)
    const int wid = tid >> 6, lane = tid & 63;
    const int q = lane >> 4, r16 = lane & 15;

    f32x4 da[4] = {{0.f,0.f,0.f,0.f},{0.f,0.f,0.f,0.f},{0.f,0.f,0.f,0.f},{0.f,0.f,0.f,0.f}};
    if (wid == 0) {
        // psi_a: M=16(e), N=64, K=64
        #pragma unroll
        for (int ks = 0; ks < 2; ++ks) {
            bf16x8 af = *(const bf16x8*)&SYA[r16 * 72 + ks * 32 + q * 8];
            #pragma unroll
            for (int n = 0; n < 4; ++n) {
                bf16x8 bf = *(const bf16x8*)((const short*)Wa + (n * 16 + r16) * 64 + ks * 32 + q * 8);
                da[n] = __builtin_amdgcn_mfma_f32_16x16x32_bf16(af, bf, da[n], 0, 0, 0);
            }
        }
    } else if (wid == 1) {
        // psi_v: M=48(e,i), N=32, K=96
        f32x4 dv[3][2] = {};
        #pragma unroll
        for (int ks = 0; ks < 3; ++ks) {
            bf16x8 av[3], bv[2];
            #pragma unroll
            for (int m = 0; m < 3; ++m)
                av[m] = *(const bf16x8*)&SYV[(m * 16 + r16) * 104 + ks * 32 + q * 8];
            #pragma unroll
            for (int n = 0; n < 2; ++n)
                bv[n] = *(const bf16x8*)((const short*)Wv + (n * 16 + r16) * 96 + ks * 32 + q * 8);
            #pragma unroll
            for (int m = 0; m < 3; ++m)
                #pragma unroll
                for (int n = 0; n < 2; ++n)
                    dv[m][n] = __builtin_amdgcn_mfma_f32_16x16x32_bf16(av[m], bv[n], dv[m][n], 0, 0, 0);
        }
        #pragma unroll
        for (int m = 0; m < 3; ++m)
            #pragma unroll
            for (int n = 0; n < 2; ++n)
                #pragma unroll
                for (int jj = 0; jj < 4; ++jj) {
                    int row = m * 16 + q * 4 + jj;
                    int el = row / 3, i = row % 3;
                    if (e0 + el < E)
                        atomicAdd(&acc_v[(size_t)SSRC[el] * 96 + (n * 16 + r16) * 3 + i], dv[m][n][jj]);
                }
    } else {
        // psi_d: M=144(e,ij), N=16, K=96 — split 5/4 M-tiles across waves 2/3
        const int mstart = (wid == 2) ? 0 : 5;
        const int mcnt = (wid == 2) ? 5 : 4;
        f32x4 dd[5] = {};
        #pragma unroll
        for (int ks = 0; ks < 3; ++ks) {
            bf16x8 bf = *(const bf16x8*)((const short*)Wd + r16 * 96 + ks * 32 + q * 8);
            for (int mi = 0; mi < mcnt; ++mi) {
                bf16x8 af = *(const bf16x8*)&SYD[((mstart + mi) * 16 + r16) * 104 + ks * 32 + q * 8];
                dd[mi] = __builtin_amdgcn_mfma_f32_16x16x32_bf16(af, bf, dd[mi], 0, 0, 0);
            }
        }
        for (int mi = 0; mi < mcnt; ++mi)
            #pragma unroll
            for (int jj = 0; jj < 4; ++jj) {
                int row = (mstart + mi) * 16 + q * 4 + jj;
                int el = row / 9, ij = row % 9;
                if (e0 + el < E)
                    atomicAdd(&acc_d[(size_t)SSRC[el] * 144 + r16 * 9 + ij], dd[mi][jj]);
            }
    }
    __syncthreads();   // b2: all y reads done (SYV/SYD now reusable)

    if (wid == 0) {
        #pragma unroll
        for (int n = 0; n < 4; ++n)
            #pragma unroll
            for (int jj = 0; jj < 4; ++jj)
                SPSIA[(q * 4 + jj) * 72 + n * 16 + r16] = f2bb(da[n][jj]);
    }
    __syncthreads();   // b3: psi_a available

    // ---- phase 3: fused MLP (M=16, all waves; wave splits N)
    // L1: h1 = lrelu(psia @ W1^T + b1), K=64, N=128
    {
        f32x4 h1a[2] = {};
        #pragma unroll
        for (int ks = 0; ks < 2; ++ks) {
            bf16x8 af = *(const bf16x8*)&SPSIA[r16 * 72 + ks * 32 + q * 8];
            #pragma unroll
            for (int n = 0; n < 2; ++n) {
                int col = wid * 32 + n * 16 + r16;
                bf16x8 bf = *(const bf16x8*)((const short*)Wb1 + col * 64 + ks * 32 + q * 8);
                h1a[n] = __builtin_amdgcn_mfma_f32_16x16x32_bf16(af, bf, h1a[n], 0, 0, 0);
            }
        }
        #pragma unroll
        for (int n = 0; n < 2; ++n) {
            int col = wid * 32 + n * 16 + r16;
            float bias = b1[col];
            #pragma unroll
            for (int jj = 0; jj < 4; ++jj) {
                float v = h1a[n][jj] + bias;
                v = v >= 0.f ? v : 0.1f * v;
                SH1[(q * 4 + jj) * 136 + col] = f2bb(v);
            }
        }
    }
    __syncthreads();   // b4: h1 ready
    // L2: h2 = lrelu(h1 @ W2^T + b2), K=128, N=128  (SH2 disjoint from SH1)
    {
        f32x4 h2a[2] = {};
        #pragma unroll
        for (int ks = 0; ks < 4; ++ks) {
            bf16x8 af = *(const bf16x8*)&SH1[r16 * 136 + ks * 32 + q * 8];
            #pragma unroll
            for (int n = 0; n < 2; ++n) {
                int col = wid * 32 + n * 16 + r16;
                bf16x8 bf = *(const bf16x8*)((const short*)Wb2 + col * 128 + ks * 32 + q * 8);
                h2a[n] = __builtin_amdgcn_mfma_f32_16x16x32_bf16(af, bf, h2a[n], 0, 0, 0);
            }
        }
        #pragma unroll
        for (int n = 0; n < 2; ++n) {
            int col = wid * 32 + n * 16 + r16;
            float bias = b2[col];
            #pragma unroll
            for (int jj = 0; jj < 4; ++jj) {
                float v = h2a[n][jj] + bias;
                v = v >= 0.f ? v : 0.1f * v;
                SH2[(q * 4 + jj) * 136 + col] = f2bb(v);
            }
        }
    }
    __syncthreads();   // b5: h2 ready
    // L3: out = psia + psia @ Wdir^T + h2 @ W3^T + b3 -> scatter
    {
        f32x4 o3 = {0.f, 0.f, 0.f, 0.f};
        const int col3 = wid * 16 + r16;
        #pragma unroll
        for (int ks = 0; ks < 4; ++ks) {
            bf16x8 af = *(const bf16x8*)&SH2[r16 * 136 + ks * 32 + q * 8];
            bf16x8 bf = *(const bf16x8*)((const short*)Wb3 + col3 * 128 + ks * 32 + q * 8);
            o3 = __builtin_amdgcn_mfma_f32_16x16x32_bf16(af, bf, o3, 0, 0, 0);
        }
        #pragma unroll
        for (int ks = 0; ks < 2; ++ks) {
            bf16x8 af = *(const bf16x8*)&SPSIA[r16 * 72 + ks * 32 + q * 8];
            bf16x8 bf = *(const bf16x8*)((const short*)Wbdir + col3 * 64 + ks * 32 + q * 8);
            o3 = __builtin_amdgcn_mfma_f32_16x16x32_bf16(af, bf, o3, 0, 0, 0);
        }
        float bias = b3[col3];
        #pragma unroll
        for (int jj = 0; jj < 4; ++jj) {
            int row = q * 4 + jj;
            int e = e0 + row;
            if (e < E) {
                float v = o3[jj] + bias + bb2f(SPSIA[row * 72 + col3]);
                atomicAdd(&acc_a[(size_t)SSRC[row] * 64 + col3], v);
            }
        }
    }
}

// ----------------------------------------------------------- finalize ----
__global__ void finalize(const float* __restrict__ acc, float* __restrict__ out, int n) {
    int i = blockIdx.x * blockDim.x + threadIdx.x;
    int stride = gridDim.x * blockDim.x;
    for (; i < n; i += stride) out[i] = 0.1f * acc[i];
}

// -------------------------------------------------------------- launch ----
extern "C" void kernel_launch(void* const* d_in, const int* in_sizes, int n_in,
                              void* d_out, int out_size, void* d_ws, size_t ws_size,
                              hipStream_t stream) {
    const float* r_ij = (const float*)d_in[0];
    const float* x_a  = (const float*)d_in[1];
    const float* x_v  = (const float*)d_in[2];
    const float* x_d  = (const float*)d_in[3];
    const float* W_L0 = (const float*)d_in[4];
    const float* W_L1 = (const float*)d_in[5];
    const float* W_L2 = (const float*)d_in[6];
    const float* W000 = (const float*)d_in[7];
    const float* W110 = (const float*)d_in[8];
    const float* W220 = (const float*)d_in[9];
    const float* W011 = (const float*)d_in[10];
    const float* W101 = (const float*)d_in[11];
    const float* W121 = (const float*)d_in[12];
    const float* W211 = (const float*)d_in[13];
    const float* W022 = (const float*)d_in[14];
    const float* W202 = (const float*)d_in[15];
    const float* W112 = (const float*)d_in[16];
    const float* W222 = (const float*)d_in[17];
    const float* W111 = (const float*)d_in[18];
    const float* W212 = (const float*)d_in[19];
    const float* Wenc = (const float*)d_in[20];
    const float* benc = (const float*)d_in[21];
    const float* Wdir = (const float*)d_in[22];
    const float* W1   = (const float*)d_in[23];
    const float* b1   = (const float*)d_in[24];
    const float* W2   = (const float*)d_in[25];
    const float* b2   = (const float*)d_in[26];
    const float* W3   = (const float*)d_in[27];
    const float* b3   = (const float*)d_in[28];
    const int* src    = (const int*)d_in[29];
    const int* dst    = (const int*)d_in[30];

    const int E = in_sizes[29];
    const int N = in_sizes[1] / 64;

    // ws layout
    float* acc   = (float*)d_ws;                       // N*304 f32
    float* acc_a = acc;
    float* acc_v = acc + (size_t)N * 64;
    float* acc_d = acc + (size_t)N * 160;
    float* Pa    = acc + (size_t)N * 304;              // N*16
    float* Pv    = Pa + (size_t)N * 16;                // N*48
    float* Pd    = Pv + (size_t)N * 48;                // N*144
    bf16*  Wb    = (bf16*)(Pd + (size_t)N * 144);      // 45568 bf16
    const bf16* Wa_p    = Wb;
    const bf16* Wv_p    = Wb + 4096;
    const bf16* Wd_p    = Wb + 7168;
    const bf16* Wb1_p   = Wb + 8704;
    const bf16* Wb2_p   = Wb + 16896;
    const bf16* Wb3_p   = Wb + 33280;
    const bf16* Wbdir_p = Wb + 41472;

    const int accN = N * 304;
    zero_f32<<<2048, 256, 0, stream>>>(acc, accN);
    prep_w<<<178, 256, 0, stream>>>(W000, W110, W220, W011, W101, W121, W211, W111,
                                    W022, W202, W112, W222, W212, W1, W2, W3, Wdir, Wb);
    node_proj<<<(N * 208 + 255) / 256, 256, 0, stream>>>(x_a, x_v, x_d, W_L0, W_L1, W_L2,
                                                         Pa, Pv, Pd, N);
    edge_mfma<<<(E + 15) / 16, 256, 0, stream>>>(
        r_ij, Pa, Pv, Pd, Wenc, benc,
        Wa_p, Wv_p, Wd_p, Wb1_p, Wb2_p, Wb3_p, Wbdir_p,
        b1, b2, b3, src, dst, acc_a, acc_v, acc_d, E);
    finalize<<<2048, 256, 0, stream>>>(acc, (float*)d_out, accN);
}

// Round 6
// 284.747 us; speedup vs baseline: 10.8053x; 2.3127x over previous
//
#include <hip/hip_runtime.h>
#include <hip/hip_bf16.h>

typedef __hip_bfloat16 bf16;
typedef __attribute__((ext_vector_type(8))) short bf16x8;
typedef __attribute__((ext_vector_type(4))) float f32x4;

__device__ __forceinline__ short f2bb(float x) {
    bf16 h = __float2bfloat16(x);
    return *reinterpret_cast<short*>(&h);
}
__device__ __forceinline__ float bb2f(short s) {
    bf16 h = *reinterpret_cast<bf16*>(&s);
    return __bfloat162float(h);
}

// ---------------------------------------------------------------- zero ----
__global__ void zero_i32(int* p, int n) {
    int i = blockIdx.x * blockDim.x + threadIdx.x;
    int stride = gridDim.x * blockDim.x;
    for (; i < n; i += stride) p[i] = 0;
}

// -------------------------------------------------------------- prep_w ----
// pack all GEMM weights as bf16 [out][k] with K zero-padded (see round-5 map)
__global__ void prep_w(
    const float* __restrict__ W000, const float* __restrict__ W110, const float* __restrict__ W220,
    const float* __restrict__ W011, const float* __restrict__ W101, const float* __restrict__ W121,
    const float* __restrict__ W211, const float* __restrict__ W111,
    const float* __restrict__ W022, const float* __restrict__ W202, const float* __restrict__ W112,
    const float* __restrict__ W222, const float* __restrict__ W212,
    const float* __restrict__ W1, const float* __restrict__ W2, const float* __restrict__ W3,
    const float* __restrict__ Wdir, bf16* __restrict__ out) {
    int i = blockIdx.x * 256 + threadIdx.x;
    if (i >= 45568) return;
    float v = 0.f;
    if (i < 4096) {
        int o = i >> 6, k = i & 63;
        if (k < 48) {
            int t = k >> 4, c = k & 15;
            const float* W = (t == 0) ? W000 : (t == 1) ? W110 : W220;
            v = W[o * 16 + c];
        }
    } else if (i < 7168) {
        int r = i - 4096, ch = r / 96, k = r % 96;
        if (k < 80) {
            int t = k >> 4, c = k & 15;
            const float* W = (t == 0) ? W011 : (t == 1) ? W101 : (t == 2) ? W121 : (t == 3) ? W211 : W111;
            v = W[ch * 16 + c];
        }
    } else if (i < 8704) {
        int r = i - 7168, ch = r / 96, k = r % 96;
        if (k < 80) {
            int t = k >> 4, c = k & 15;
            const float* W = (t == 0) ? W022 : (t == 1) ? W202 : (t == 2) ? W112 : (t == 3) ? W222 : W212;
            v = W[ch * 16 + c];
        }
    } else if (i < 16896) v = W1[i - 8704];
    else if (i < 33280) v = W2[i - 16896];
    else if (i < 41472) v = W3[i - 33280];
    else v = Wdir[i - 41472];
    out[i] = __float2bfloat16(v);
}

// ---------------------------------------------------------- node_proj ----
__global__ void node_proj(const float* __restrict__ xa, const float* __restrict__ xv,
                          const float* __restrict__ xd,
                          const float* __restrict__ WL0, const float* __restrict__ WL1,
                          const float* __restrict__ WL2,
                          float* __restrict__ Pa, float* __restrict__ Pv,
                          float* __restrict__ Pd, int N) {
    int t = blockIdx.x * blockDim.x + threadIdx.x;
    int total = N * 208;
    if (t >= total) return;
    int n = t / 208, s = t % 208;
    if (s < 16) {
        float acc = 0.f;
        const float* x = xa + n * 64;
        const float* w = WL0 + s * 64;
        for (int d = 0; d < 64; ++d) acc += w[d] * x[d];
        Pa[n * 16 + s] = acc;
    } else if (s < 64) {
        int idx = s - 16, c = idx / 3, i = idx % 3;
        float acc = 0.f;
        const float* w = WL1 + c * 32;
        for (int d = 0; d < 32; ++d) acc += w[d] * xv[(n * 32 + d) * 3 + i];
        Pv[n * 48 + idx] = acc;
    } else {
        int idx = s - 64, c = idx / 9, ij = idx % 9;
        float acc = 0.f;
        const float* w = WL2 + c * 16;
        for (int d = 0; d < 16; ++d) acc += w[d] * xd[(n * 16 + d) * 9 + ij];
        Pd[n * 144 + idx] = acc;
    }
}

// --------------------------------------------------------------- CSR ----
__global__ void hist_src(const int* __restrict__ src, int* __restrict__ cnt, int E) {
    int i = blockIdx.x * 256 + threadIdx.x;
    if (i < E) atomicAdd(&cnt[src[i]], 1);
}

__global__ void scan_rows(const int* __restrict__ cnt, int* __restrict__ rowstart, int N) {
    __shared__ int ps[256];
    int t = threadIdx.x;
    int chunk = (N + 255) / 256;
    int base = t * chunk;
    int s = 0;
    for (int i = 0; i < chunk; ++i) { int idx = base + i; if (idx < N) s += cnt[idx]; }
    ps[t] = s;
    __syncthreads();
    for (int off = 1; off < 256; off <<= 1) {
        int v = (t >= off) ? ps[t - off] : 0;
        __syncthreads();
        ps[t] += v;
        __syncthreads();
    }
    int run = (t > 0) ? ps[t - 1] : 0;
    for (int i = 0; i < chunk; ++i) {
        int idx = base + i;
        if (idx < N) { rowstart[idx] = run; run += cnt[idx]; }
    }
    if (t == 255) rowstart[N] = run;
}

__global__ void fill_slot(const int* __restrict__ src, const int* __restrict__ rowstart,
                          int* __restrict__ cursor, int* __restrict__ slot, int E) {
    int i = blockIdx.x * 256 + threadIdx.x;
    if (i < E) slot[i] = rowstart[src[i]] + atomicAdd(&cursor[src[i]], 1);
}

// ---------------------------------------------------------- edge_mfma ----
// 16 edges/block. phase1: y-build (bf16, MFMA-A layout LDS). phase2: tensor
// GEMMs on MFMA (wave0 psi_a, wave1 psi_v, waves2/3 psi_d) -> SPSI staging.
// phase3: fused MLP on psi_a -> SPSI. Then one coalesced psi-row store per
// edge at CSR position slot[e]. Zero f32 atomics.
__global__ __launch_bounds__(256) void edge_mfma(
    const float* __restrict__ r_ij,
    const float* __restrict__ Pa, const float* __restrict__ Pv, const float* __restrict__ Pd,
    const float* __restrict__ Wenc, const float* __restrict__ benc,
    const bf16* __restrict__ Wa, const bf16* __restrict__ Wv, const bf16* __restrict__ Wd,
    const bf16* __restrict__ Wb1, const bf16* __restrict__ Wb2,
    const bf16* __restrict__ Wb3, const bf16* __restrict__ Wbdir,
    const float* __restrict__ b1, const float* __restrict__ b2, const float* __restrict__ b3,
    const int* __restrict__ slot, const int* __restrict__ dst,
    short* __restrict__ psi, int E)
{
    __shared__ __align__(16) char smem[52032];
    short* SYA   = (short*)smem;            // [16][72]  psi_a A-operand
    short* SYV   = (short*)(smem + 2304);   // [48][104] psi_v A
    short* SYD   = (short*)(smem + 12288);  // [144][104] psi_d A
    short* SPSIA = SYV;                     // [16][72]  psi_a result (post-b2)
    short* SH1   = (short*)(smem + 4608);   // [16][136]
    short* SH2   = SYD;                     // [16][136]
    short* SPSI  = (short*)(smem + 42240);  // [16][304] staged psi rows
    int*   SSLOT = (int*)(smem + 51968);    // [16]

    const int tid = threadIdx.x;
    const int e0 = blockIdx.x * 16;

    // ---- zero K-pad columns
    {
        int x = tid;
        if (x < 256) SYA[(x >> 4) * 72 + 48 + (x & 15)] = 0;
        for (int y = tid; y < 768; y += 256)  SYV[(y / 16) * 104 + 80 + (y & 15)] = 0;
        for (int y = tid; y < 2304; y += 256) SYD[(y / 16) * 104 + 80 + (y & 15)] = 0;
    }

    // ---- phase 1: y-build. thread = (local edge le, channel c)
    {
        const int le = tid >> 4, c = tid & 15;
        const int e = e0 + le;
        if (e < E) {
            const int j = dst[e];
            if (c == 0) SSLOT[le] = slot[e];
            float vx = 7.f * r_ij[e * 3 + 0];
            float vy = 7.f * r_ij[e * 3 + 1];
            float vz = 7.f * r_ij[e * 3 + 2];
            float nn = sqrtf(vx * vx + vy * vy + vz * vz);
            float sc = tanhf(nn) / (nn + 1e-12f);
            float rr[3] = {vx * sc, vy * sc, vz * sc};
            float x8 = nn * (8.f / 7.f);
            float rad = benc[c];
            #pragma unroll
            for (int m = 0; m < 8; ++m) {
                float tt = x8 - (float)m;
                rad += __expf(-0.5f * tt * tt) * Wenc[c * 8 + m];
            }
            float xa = Pa[j * 16 + c];
            float xv[3], xd[9];
            #pragma unroll
            for (int i = 0; i < 3; ++i) xv[i] = Pv[j * 48 + c * 3 + i];
            #pragma unroll
            for (int k = 0; k < 9; ++k) xd[k] = Pd[j * 144 + c * 9 + k];
            float dotv = xv[0] * rr[0] + xv[1] * rr[1] + xv[2] * rr[2];
            float mv[3];
            #pragma unroll
            for (int i = 0; i < 3; ++i)
                mv[i] = xd[i * 3] * rr[0] + xd[i * 3 + 1] * rr[1] + xd[i * 3 + 2] * rr[2];
            float quad = mv[0] * rr[0] + mv[1] * rr[1] + mv[2] * rr[2];
            SYA[le * 72 + c]      = f2bb(xa * rad);
            SYA[le * 72 + 16 + c] = f2bb(rad * dotv);
            SYA[le * 72 + 32 + c] = f2bb(rad * quad);
            #pragma unroll
            for (int i = 0; i < 3; ++i) {
                int row = (le * 3 + i) * 104;
                int i1 = (i + 1) % 3, i2 = (i + 2) % 3;
                SYV[row + c]      = f2bb(xa * rad * rr[i]);
                SYV[row + 16 + c] = f2bb(rad * xv[i]);
                SYV[row + 32 + c] = f2bb(rad * dotv * rr[i]);
                SYV[row + 48 + c] = f2bb(rad * mv[i]);
                SYV[row + 64 + c] = f2bb(rad * (xv[i1] * rr[i2] - xv[i2] * rr[i1]));
            }
            #pragma unroll
            for (int i = 0; i < 3; ++i) {
                int i1 = (i + 1) % 3, i2 = (i + 2) % 3;
                #pragma unroll
                for (int jj = 0; jj < 3; ++jj) {
                    int row = (le * 9 + i * 3 + jj) * 104;
                    SYD[row + c]      = f2bb(xa * rad * rr[i] * rr[jj]);
                    SYD[row + 16 + c] = f2bb(rad * xd[i * 3 + jj]);
                    SYD[row + 32 + c] = f2bb(rad * xv[i] * rr[jj]);
                    SYD[row + 48 + c] = f2bb(rad * mv[i] * rr[jj]);
                    SYD[row + 64 + c] = f2bb(rad * (xd[i1 * 3 + jj] * rr[i2] - xd[i2 * 3 + jj] * rr[i1]));
                }
            }
        }
    }
    __syncthreads();   // b1: y ready

    // ---- phase 2: tensor GEMMs
    const int wid = tid >> 6, lane = tid & 63;
    const int q = lane >> 4, r16 = lane & 15;

    f32x4 da[4] = {{0.f,0.f,0.f,0.f},{0.f,0.f,0.f,0.f},{0.f,0.f,0.f,0.f},{0.f,0.f,0.f,0.f}};
    if (wid == 0) {
        // psi_a: M=16(e), N=64, K=64
        #pragma unroll
        for (int ks = 0; ks < 2; ++ks) {
            bf16x8 af = *(const bf16x8*)&SYA[r16 * 72 + ks * 32 + q * 8];
            #pragma unroll
            for (int n = 0; n < 4; ++n) {
                bf16x8 bf = *(const bf16x8*)((const short*)Wa + (n * 16 + r16) * 64 + ks * 32 + q * 8);
                da[n] = __builtin_amdgcn_mfma_f32_16x16x32_bf16(af, bf, da[n], 0, 0, 0);
            }
        }
    } else if (wid == 1) {
        // psi_v: M=48(e,i), N=32, K=96 -> SPSI v-segment
        f32x4 dv[3][2] = {};
        #pragma unroll
        for (int ks = 0; ks < 3; ++ks) {
            bf16x8 av[3], bv[2];
            #pragma unroll
            for (int m = 0; m < 3; ++m)
                av[m] = *(const bf16x8*)&SYV[(m * 16 + r16) * 104 + ks * 32 + q * 8];
            #pragma unroll
            for (int n = 0; n < 2; ++n)
                bv[n] = *(const bf16x8*)((const short*)Wv + (n * 16 + r16) * 96 + ks * 32 + q * 8);
            #pragma unroll
            for (int m = 0; m < 3; ++m)
                #pragma unroll
                for (int n = 0; n < 2; ++n)
                    dv[m][n] = __builtin_amdgcn_mfma_f32_16x16x32_bf16(av[m], bv[n], dv[m][n], 0, 0, 0);
        }
        #pragma unroll
        for (int m = 0; m < 3; ++m)
            #pragma unroll
            for (int n = 0; n < 2; ++n)
                #pragma unroll
                for (int jj = 0; jj < 4; ++jj) {
                    int row = m * 16 + q * 4 + jj;
                    int el = row / 3, i = row % 3;
                    SPSI[el * 304 + 64 + (n * 16 + r16) * 3 + i] = f2bb(dv[m][n][jj]);
                }
    } else {
        // psi_d: M=144(e,ij), N=16, K=96 -> SPSI d-segment
        const int mstart = (wid == 2) ? 0 : 5;
        const int mcnt = (wid == 2) ? 5 : 4;
        f32x4 dd[5] = {};
        #pragma unroll
        for (int ks = 0; ks < 3; ++ks) {
            bf16x8 bf = *(const bf16x8*)((const short*)Wd + r16 * 96 + ks * 32 + q * 8);
            for (int mi = 0; mi < mcnt; ++mi) {
                bf16x8 af = *(const bf16x8*)&SYD[((mstart + mi) * 16 + r16) * 104 + ks * 32 + q * 8];
                dd[mi] = __builtin_amdgcn_mfma_f32_16x16x32_bf16(af, bf, dd[mi], 0, 0, 0);
            }
        }
        for (int mi = 0; mi < mcnt; ++mi)
            #pragma unroll
            for (int jj = 0; jj < 4; ++jj) {
                int row = (mstart + mi) * 16 + q * 4 + jj;
                int el = row / 9, ij = row % 9;
                SPSI[el * 304 + 160 + r16 * 9 + ij] = f2bb(dd[mi][jj]);
            }
    }
    __syncthreads();   // b2: y reads done, SYV/SYD reusable

    if (wid == 0) {
        #pragma unroll
        for (int n = 0; n < 4; ++n)
            #pragma unroll
            for (int jj = 0; jj < 4; ++jj)
                SPSIA[(q * 4 + jj) * 72 + n * 16 + r16] = f2bb(da[n][jj]);
    }
    __syncthreads();   // b3: psi_a available

    // ---- phase 3: fused MLP (M=16, waves split N)
    {
        f32x4 h1a[2] = {};
        #pragma unroll
        for (int ks = 0; ks < 2; ++ks) {
            bf16x8 af = *(const bf16x8*)&SPSIA[r16 * 72 + ks * 32 + q * 8];
            #pragma unroll
            for (int n = 0; n < 2; ++n) {
                int col = wid * 32 + n * 16 + r16;
                bf16x8 bf = *(const bf16x8*)((const short*)Wb1 + col * 64 + ks * 32 + q * 8);
                h1a[n] = __builtin_amdgcn_mfma_f32_16x16x32_bf16(af, bf, h1a[n], 0, 0, 0);
            }
        }
        #pragma unroll
        for (int n = 0; n < 2; ++n) {
            int col = wid * 32 + n * 16 + r16;
            float bias = b1[col];
            #pragma unroll
            for (int jj = 0; jj < 4; ++jj) {
                float v = h1a[n][jj] + bias;
                v = v >= 0.f ? v : 0.1f * v;
                SH1[(q * 4 + jj) * 136 + col] = f2bb(v);
            }
        }
    }
    __syncthreads();   // b4: h1 ready
    {
        f32x4 h2a[2] = {};
        #pragma unroll
        for (int ks = 0; ks < 4; ++ks) {
            bf16x8 af = *(const bf16x8*)&SH1[r16 * 136 + ks * 32 + q * 8];
            #pragma unroll
            for (int n = 0; n < 2; ++n) {
                int col = wid * 32 + n * 16 + r16;
                bf16x8 bf = *(const bf16x8*)((const short*)Wb2 + col * 128 + ks * 32 + q * 8);
                h2a[n] = __builtin_amdgcn_mfma_f32_16x16x32_bf16(af, bf, h2a[n], 0, 0, 0);
            }
        }
        #pragma unroll
        for (int n = 0; n < 2; ++n) {
            int col = wid * 32 + n * 16 + r16;
            float bias = b2[col];
            #pragma unroll
            for (int jj = 0; jj < 4; ++jj) {
                float v = h2a[n][jj] + bias;
                v = v >= 0.f ? v : 0.1f * v;
                SH2[(q * 4 + jj) * 136 + col] = f2bb(v);
            }
        }
    }
    __syncthreads();   // b5: h2 ready
    {
        f32x4 o3 = {0.f, 0.f, 0.f, 0.f};
        const int col3 = wid * 16 + r16;
        #pragma unroll
        for (int ks = 0; ks < 4; ++ks) {
            bf16x8 af = *(const bf16x8*)&SH2[r16 * 136 + ks * 32 + q * 8];
            bf16x8 bf = *(const bf16x8*)((const short*)Wb3 + col3 * 128 + ks * 32 + q * 8);
            o3 = __builtin_amdgcn_mfma_f32_16x16x32_bf16(af, bf, o3, 0, 0, 0);
        }
        #pragma unroll
        for (int ks = 0; ks < 2; ++ks) {
            bf16x8 af = *(const bf16x8*)&SPSIA[r16 * 72 + ks * 32 + q * 8];
            bf16x8 bf = *(const bf16x8*)((const short*)Wbdir + col3 * 64 + ks * 32 + q * 8);
            o3 = __builtin_amdgcn_mfma_f32_16x16x32_bf16(af, bf, o3, 0, 0, 0);
        }
        float bias = b3[col3];
        #pragma unroll
        for (int jj = 0; jj < 4; ++jj) {
            int row = q * 4 + jj;
            float v = o3[jj] + bias + bb2f(SPSIA[row * 72 + col3]);
            SPSI[row * 304 + col3] = f2bb(v);
        }
    }
    __syncthreads();   // b6: SPSI complete

    // ---- coalesced psi-row store at CSR slot
    {
        const uint32_t* S32 = (const uint32_t*)SPSI;
        uint32_t* P32 = (uint32_t*)psi;
        for (int idx = tid; idx < 16 * 152; idx += 256) {
            int le = idx / 152, k = idx - le * 152;
            if (e0 + le < E)
                P32[(size_t)SSLOT[le] * 152 + k] = S32[le * 152 + k];
        }
    }
}

// -------------------------------------------------------------- gather ----
// block = node n; rows [rowstart[n], rowstart[n+1]) are contiguous in psi.
__global__ __launch_bounds__(256) void gather(
    const short* __restrict__ psi, const int* __restrict__ rowstart,
    float* __restrict__ out, int N) {
    int n = blockIdx.x, t = threadIdx.x;
    if (t >= 152) return;
    int s0 = rowstart[n], s1 = rowstart[n + 1];
    const uint32_t* p32 = (const uint32_t*)psi;
    float a0 = 0.f, a1 = 0.f;
    for (int s = s0; s < s1; ++s) {
        uint32_t u = p32[(size_t)s * 152 + t];
        a0 += __uint_as_float(u << 16);
        a1 += __uint_as_float(u & 0xffff0000u);
    }
    int f = 2 * t;
    float2 v = make_float2(0.1f * a0, 0.1f * a1);
    if (f < 64)       *(float2*)&out[(size_t)n * 64 + f] = v;
    else if (f < 160) *(float2*)&out[(size_t)N * 64 + (size_t)n * 96 + (f - 64)] = v;
    else              *(float2*)&out[(size_t)N * 160 + (size_t)n * 144 + (f - 160)] = v;
}

// -------------------------------------------------------------- launch ----
extern "C" void kernel_launch(void* const* d_in, const int* in_sizes, int n_in,
                              void* d_out, int out_size, void* d_ws, size_t ws_size,
                              hipStream_t stream) {
    const float* r_ij = (const float*)d_in[0];
    const float* x_a  = (const float*)d_in[1];
    const float* x_v  = (const float*)d_in[2];
    const float* x_d  = (const float*)d_in[3];
    const float* W_L0 = (const float*)d_in[4];
    const float* W_L1 = (const float*)d_in[5];
    const float* W_L2 = (const float*)d_in[6];
    const float* W000 = (const float*)d_in[7];
    const float* W110 = (const float*)d_in[8];
    const float* W220 = (const float*)d_in[9];
    const float* W011 = (const float*)d_in[10];
    const float* W101 = (const float*)d_in[11];
    const float* W121 = (const float*)d_in[12];
    const float* W211 = (const float*)d_in[13];
    const float* W022 = (const float*)d_in[14];
    const float* W202 = (const float*)d_in[15];
    const float* W112 = (const float*)d_in[16];
    const float* W222 = (const float*)d_in[17];
    const float* W111 = (const float*)d_in[18];
    const float* W212 = (const float*)d_in[19];
    const float* Wenc = (const float*)d_in[20];
    const float* benc = (const float*)d_in[21];
    const float* Wdir = (const float*)d_in[22];
    const float* W1   = (const float*)d_in[23];
    const float* b1   = (const float*)d_in[24];
    const float* W2   = (const float*)d_in[25];
    const float* b2   = (const float*)d_in[26];
    const float* W3   = (const float*)d_in[27];
    const float* b3   = (const float*)d_in[28];
    const int* src    = (const int*)d_in[29];
    const int* dst    = (const int*)d_in[30];

    const int E = in_sizes[29];
    const int N = in_sizes[1] / 64;

    // ws layout
    float* Pa     = (float*)d_ws;                    // N*16
    float* Pv     = Pa + (size_t)N * 16;             // N*48
    float* Pd     = Pv + (size_t)N * 48;             // N*144
    bf16*  Wb     = (bf16*)(Pd + (size_t)N * 144);   // 45568 bf16
    int*   cnt    = (int*)(Wb + 45568);              // N
    int*   cursor = cnt + N;                         // N
    int*   rowst  = cursor + N;                      // N+1
    int*   slot   = rowst + N + 1;                   // E
    short* psi    = (short*)(slot + E);              // E*304 bf16

    const bf16* Wa_p    = Wb;
    const bf16* Wv_p    = Wb + 4096;
    const bf16* Wd_p    = Wb + 7168;
    const bf16* Wb1_p   = Wb + 8704;
    const bf16* Wb2_p   = Wb + 16896;
    const bf16* Wb3_p   = Wb + 33280;
    const bf16* Wbdir_p = Wb + 41472;

    zero_i32<<<80, 256, 0, stream>>>(cnt, 2 * N);    // cnt + cursor
    prep_w<<<178, 256, 0, stream>>>(W000, W110, W220, W011, W101, W121, W211, W111,
                                    W022, W202, W112, W222, W212, W1, W2, W3, Wdir, Wb);
    node_proj<<<(N * 208 + 255) / 256, 256, 0, stream>>>(x_a, x_v, x_d, W_L0, W_L1, W_L2,
                                                         Pa, Pv, Pd, N);
    hist_src<<<(E + 255) / 256, 256, 0, stream>>>(src, cnt, E);
    scan_rows<<<1, 256, 0, stream>>>(cnt, rowst, N);
    fill_slot<<<(E + 255) / 256, 256, 0, stream>>>(src, rowst, cursor, slot, E);
    edge_mfma<<<(E + 15) / 16, 256, 0, stream>>>(
        r_ij, Pa, Pv, Pd, Wenc, benc,
        Wa_p, Wv_p, Wd_p, Wb1_p, Wb2_p, Wb3_p, Wbdir_p,
        b1, b2, b3, slot, dst, psi, E);
    gather<<<N, 256, 0, stream>>>(psi, rowst, (float*)d_out, N);
}

// Round 7
// 245.064 us; speedup vs baseline: 12.5550x; 1.1619x over previous
//
#include <hip/hip_runtime.h>
#include <hip/hip_bf16.h>

typedef __hip_bfloat16 bf16;
typedef __attribute__((ext_vector_type(8))) short bf16x8;
typedef __attribute__((ext_vector_type(4))) float f32x4;

__device__ __forceinline__ short f2bb(float x) {
    bf16 h = __float2bfloat16(x);
    return *reinterpret_cast<short*>(&h);
}
__device__ __forceinline__ float bb2f(short s) {
    bf16 h = *reinterpret_cast<bf16*>(&s);
    return __bfloat162float(h);
}

// ---------------------------------------------------------------- zero ----
__global__ void zero_i32(int* p, int n) {
    int i = blockIdx.x * blockDim.x + threadIdx.x;
    int stride = gridDim.x * blockDim.x;
    for (; i < n; i += stride) p[i] = 0;
}

// -------------------------------------------------------------- prep_w ----
// pack all GEMM weights as bf16 [out][k] with K zero-padded
__global__ void prep_w(
    const float* __restrict__ W000, const float* __restrict__ W110, const float* __restrict__ W220,
    const float* __restrict__ W011, const float* __restrict__ W101, const float* __restrict__ W121,
    const float* __restrict__ W211, const float* __restrict__ W111,
    const float* __restrict__ W022, const float* __restrict__ W202, const float* __restrict__ W112,
    const float* __restrict__ W222, const float* __restrict__ W212,
    const float* __restrict__ W1, const float* __restrict__ W2, const float* __restrict__ W3,
    const float* __restrict__ Wdir, bf16* __restrict__ out) {
    int i = blockIdx.x * 256 + threadIdx.x;
    if (i >= 45568) return;
    float v = 0.f;
    if (i < 4096) {
        int o = i >> 6, k = i & 63;
        if (k < 48) {
            int t = k >> 4, c = k & 15;
            const float* W = (t == 0) ? W000 : (t == 1) ? W110 : W220;
            v = W[o * 16 + c];
        }
    } else if (i < 7168) {
        int r = i - 4096, ch = r / 96, k = r % 96;
        if (k < 80) {
            int t = k >> 4, c = k & 15;
            const float* W = (t == 0) ? W011 : (t == 1) ? W101 : (t == 2) ? W121 : (t == 3) ? W211 : W111;
            v = W[ch * 16 + c];
        }
    } else if (i < 8704) {
        int r = i - 7168, ch = r / 96, k = r % 96;
        if (k < 80) {
            int t = k >> 4, c = k & 15;
            const float* W = (t == 0) ? W022 : (t == 1) ? W202 : (t == 2) ? W112 : (t == 3) ? W222 : W212;
            v = W[ch * 16 + c];
        }
    } else if (i < 16896) v = W1[i - 8704];
    else if (i < 33280) v = W2[i - 16896];
    else if (i < 41472) v = W3[i - 33280];
    else v = Wdir[i - 41472];
    out[i] = __float2bfloat16(v);
}

// ---------------------------------------------------------- node_proj4 ----
// 4 nodes per block, inputs staged in LDS with coalesced loads.
__global__ __launch_bounds__(256) void node_proj4(
    const float* __restrict__ xa, const float* __restrict__ xv, const float* __restrict__ xd,
    const float* __restrict__ WL0, const float* __restrict__ WL1, const float* __restrict__ WL2,
    float* __restrict__ Pa, float* __restrict__ Pv, float* __restrict__ Pd, int N) {
    __shared__ float sxa[256], sxv[384], sxd[576];
    const int n0 = blockIdx.x * 4;
    const int tid = threadIdx.x;
    if (n0 + tid / 64 < N) sxa[tid] = xa[(size_t)n0 * 64 + tid];
    for (int i = tid; i < 384; i += 256) if (n0 + i / 96 < N)  sxv[i] = xv[(size_t)n0 * 96 + i];
    for (int i = tid; i < 576; i += 256) if (n0 + i / 144 < N) sxd[i] = xd[(size_t)n0 * 144 + i];
    __syncthreads();
    for (int o = tid; o < 832; o += 256) {
        int ln = o / 208, s = o % 208;
        int n = n0 + ln;
        if (n >= N) continue;
        if (s < 16) {
            float a = 0.f;
            const float* w = WL0 + s * 64;
            const float* x = sxa + ln * 64;
            for (int d = 0; d < 64; ++d) a += w[d] * x[d];
            Pa[(size_t)n * 16 + s] = a;
        } else if (s < 64) {
            int idx = s - 16, c = idx / 3, i = idx % 3;
            float a = 0.f;
            const float* w = WL1 + c * 32;
            const float* x = sxv + ln * 96;
            for (int d = 0; d < 32; ++d) a += w[d] * x[d * 3 + i];
            Pv[(size_t)n * 48 + idx] = a;
        } else {
            int idx = s - 64, c = idx / 9, ij = idx % 9;
            float a = 0.f;
            const float* w = WL2 + c * 16;
            const float* x = sxd + ln * 144;
            for (int d = 0; d < 16; ++d) a += w[d] * x[d * 9 + ij];
            Pd[(size_t)n * 144 + idx] = a;
        }
    }
}

// --------------------------------------------------------------- CSR ----
__global__ void hist_src(const int* __restrict__ src, int* __restrict__ cnt, int E) {
    int i = blockIdx.x * 256 + threadIdx.x;
    if (i < E) atomicAdd(&cnt[src[i]], 1);
}

__global__ void scan_rows(const int* __restrict__ cnt, int* __restrict__ rowstart, int N) {
    __shared__ int ps[256];
    int t = threadIdx.x;
    int chunk = (N + 255) / 256;
    int base = t * chunk;
    int s = 0;
    for (int i = 0; i < chunk; ++i) { int idx = base + i; if (idx < N) s += cnt[idx]; }
    ps[t] = s;
    __syncthreads();
    for (int off = 1; off < 256; off <<= 1) {
        int v = (t >= off) ? ps[t - off] : 0;
        __syncthreads();
        ps[t] += v;
        __syncthreads();
    }
    int run = (t > 0) ? ps[t - 1] : 0;
    for (int i = 0; i < chunk; ++i) {
        int idx = base + i;
        if (idx < N) { rowstart[idx] = run; run += cnt[idx]; }
    }
    if (t == 255) rowstart[N] = run;
}

__global__ void fill_slot(const int* __restrict__ src, const int* __restrict__ rowstart,
                          int* __restrict__ cursor, int* __restrict__ slot, int E) {
    int i = blockIdx.x * 256 + threadIdx.x;
    if (i < E) slot[i] = rowstart[src[i]] + atomicAdd(&cursor[src[i]], 1);
}

// ---------------------------------------------------------- edge_mfma ----
// 16 edges/block, 32.3KB LDS -> 5 blocks/CU. No K-pad columns: remainder
// K-steps use zeroed A-fragments for lanes q>=2 (B is zero-padded in global).
// psi_v/psi_d accumulators carried across b2 so the MLP/SPSI LDS region
// aliases the y-operand region.
__global__ __launch_bounds__(256) void edge_mfma(
    const float* __restrict__ r_ij,
    const float* __restrict__ Pa, const float* __restrict__ Pv, const float* __restrict__ Pd,
    const float* __restrict__ Wenc, const float* __restrict__ benc,
    const bf16* __restrict__ Wa, const bf16* __restrict__ Wv, const bf16* __restrict__ Wd,
    const bf16* __restrict__ Wb1, const bf16* __restrict__ Wb2,
    const bf16* __restrict__ Wb3, const bf16* __restrict__ Wbdir,
    const float* __restrict__ b1, const float* __restrict__ b2, const float* __restrict__ b3,
    const int* __restrict__ slot, const int* __restrict__ dst,
    short* __restrict__ psi, int E)
{
    __shared__ __align__(16) char smem[32320];
    short* SYA   = (short*)smem;            // [16][48]  K=48, no pad
    short* SYV   = (short*)(smem + 1536);   // [48][80]  K=80, no pad
    short* SYD   = (short*)(smem + 9216);   // [144][80]
    int*   SSLOT = (int*)(smem + 32256);    // [16]
    // phase-3 aliases (valid after b2; within [1536, 22272))
    short* SPSIA = (short*)(smem + 1536);   // [16][72]
    short* SH1   = (short*)(smem + 3840);   // [16][136]
    short* SH2   = (short*)(smem + 8192);   // [16][136]
    short* SPSI  = (short*)(smem + 12544);  // [16][304]

    const int tid = threadIdx.x;
    const int e0 = blockIdx.x * 16;
    const bf16x8 z8 = {};

    // ---- phase 1: y-build. thread = (local edge le, channel c)
    {
        const int le = tid >> 4, c = tid & 15;
        const int e = e0 + le;
        if (e < E) {
            const int j = dst[e];
            if (c == 0) SSLOT[le] = slot[e];
            float vx = 7.f * r_ij[e * 3 + 0];
            float vy = 7.f * r_ij[e * 3 + 1];
            float vz = 7.f * r_ij[e * 3 + 2];
            float nn = sqrtf(vx * vx + vy * vy + vz * vz);
            float sc = tanhf(nn) / (nn + 1e-12f);
            float rr[3] = {vx * sc, vy * sc, vz * sc};
            float x8 = nn * (8.f / 7.f);
            float rad = benc[c];
            #pragma unroll
            for (int m = 0; m < 8; ++m) {
                float tt = x8 - (float)m;
                rad += __expf(-0.5f * tt * tt) * Wenc[c * 8 + m];
            }
            float xa = Pa[j * 16 + c];
            float xv[3], xd[9];
            #pragma unroll
            for (int i = 0; i < 3; ++i) xv[i] = Pv[j * 48 + c * 3 + i];
            #pragma unroll
            for (int k = 0; k < 9; ++k) xd[k] = Pd[j * 144 + c * 9 + k];
            float dotv = xv[0] * rr[0] + xv[1] * rr[1] + xv[2] * rr[2];
            float mv[3];
            #pragma unroll
            for (int i = 0; i < 3; ++i)
                mv[i] = xd[i * 3] * rr[0] + xd[i * 3 + 1] * rr[1] + xd[i * 3 + 2] * rr[2];
            float quad = mv[0] * rr[0] + mv[1] * rr[1] + mv[2] * rr[2];
            SYA[le * 48 + c]      = f2bb(xa * rad);
            SYA[le * 48 + 16 + c] = f2bb(rad * dotv);
            SYA[le * 48 + 32 + c] = f2bb(rad * quad);
            #pragma unroll
            for (int i = 0; i < 3; ++i) {
                int row = (le * 3 + i) * 80;
                int i1 = (i + 1) % 3, i2 = (i + 2) % 3;
                SYV[row + c]      = f2bb(xa * rad * rr[i]);
                SYV[row + 16 + c] = f2bb(rad * xv[i]);
                SYV[row + 32 + c] = f2bb(rad * dotv * rr[i]);
                SYV[row + 48 + c] = f2bb(rad * mv[i]);
                SYV[row + 64 + c] = f2bb(rad * (xv[i1] * rr[i2] - xv[i2] * rr[i1]));
            }
            #pragma unroll
            for (int i = 0; i < 3; ++i) {
                int i1 = (i + 1) % 3, i2 = (i + 2) % 3;
                #pragma unroll
                for (int jj = 0; jj < 3; ++jj) {
                    int row = (le * 9 + i * 3 + jj) * 80;
                    SYD[row + c]      = f2bb(xa * rad * rr[i] * rr[jj]);
                    SYD[row + 16 + c] = f2bb(rad * xd[i * 3 + jj]);
                    SYD[row + 32 + c] = f2bb(rad * xv[i] * rr[jj]);
                    SYD[row + 48 + c] = f2bb(rad * mv[i] * rr[jj]);
                    SYD[row + 64 + c] = f2bb(rad * (xd[i1 * 3 + jj] * rr[i2] - xd[i2 * 3 + jj] * rr[i1]));
                }
            }
        }
    }
    __syncthreads();   // b1: y ready

    // ---- phase 2: tensor GEMMs (accumulators persist across b2)
    const int wid = tid >> 6, lane = tid & 63;
    const int q = lane >> 4, r16 = lane & 15;

    f32x4 da[4] = {};
    f32x4 dv[3][2] = {};
    f32x4 dd[5] = {};
    const int mstart = (wid == 2) ? 0 : 5;
    const int mcnt = (wid == 2) ? 5 : 4;

    if (wid == 0) {
        // psi_a: M=16, N=64, K=48 (kstep1 half)
        bf16x8 af0 = *(const bf16x8*)&SYA[r16 * 48 + q * 8];
        bf16x8 af1 = z8;
        if (q < 2) af1 = *(const bf16x8*)&SYA[r16 * 48 + 32 + q * 8];
        #pragma unroll
        for (int n = 0; n < 4; ++n) {
            bf16x8 bf0 = *(const bf16x8*)((const short*)Wa + (n * 16 + r16) * 64 + q * 8);
            bf16x8 bf1 = *(const bf16x8*)((const short*)Wa + (n * 16 + r16) * 64 + 32 + q * 8);
            da[n] = __builtin_amdgcn_mfma_f32_16x16x32_bf16(af0, bf0, da[n], 0, 0, 0);
            da[n] = __builtin_amdgcn_mfma_f32_16x16x32_bf16(af1, bf1, da[n], 0, 0, 0);
        }
    } else if (wid == 1) {
        // psi_v: M=48, N=32, K=80 (kstep2 half)
        #pragma unroll
        for (int ks = 0; ks < 3; ++ks) {
            bf16x8 av[3], bv[2];
            #pragma unroll
            for (int m = 0; m < 3; ++m) {
                if (ks < 2) av[m] = *(const bf16x8*)&SYV[(m * 16 + r16) * 80 + ks * 32 + q * 8];
                else {
                    av[m] = z8;
                    if (q < 2) av[m] = *(const bf16x8*)&SYV[(m * 16 + r16) * 80 + 64 + q * 8];
                }
            }
            #pragma unroll
            for (int n = 0; n < 2; ++n)
                bv[n] = *(const bf16x8*)((const short*)Wv + (n * 16 + r16) * 96 + ks * 32 + q * 8);
            #pragma unroll
            for (int m = 0; m < 3; ++m)
                #pragma unroll
                for (int n = 0; n < 2; ++n)
                    dv[m][n] = __builtin_amdgcn_mfma_f32_16x16x32_bf16(av[m], bv[n], dv[m][n], 0, 0, 0);
        }
    } else {
        // psi_d: M=144 (5/4 M-tiles on waves 2/3), N=16, K=80
        #pragma unroll
        for (int ks = 0; ks < 3; ++ks) {
            bf16x8 bf = *(const bf16x8*)((const short*)Wd + r16 * 96 + ks * 32 + q * 8);
            for (int mi = 0; mi < mcnt; ++mi) {
                bf16x8 af;
                if (ks < 2) af = *(const bf16x8*)&SYD[((mstart + mi) * 16 + r16) * 80 + ks * 32 + q * 8];
                else {
                    af = z8;
                    if (q < 2) af = *(const bf16x8*)&SYD[((mstart + mi) * 16 + r16) * 80 + 64 + q * 8];
                }
                dd[mi] = __builtin_amdgcn_mfma_f32_16x16x32_bf16(af, bf, dd[mi], 0, 0, 0);
            }
        }
    }
    __syncthreads();   // b2: all y reads done, SYV/SYD regions reusable

    // ---- epilogues into aliased region
    if (wid == 0) {
        #pragma unroll
        for (int n = 0; n < 4; ++n)
            #pragma unroll
            for (int jj = 0; jj < 4; ++jj)
                SPSIA[(q * 4 + jj) * 72 + n * 16 + r16] = f2bb(da[n][jj]);
    } else if (wid == 1) {
        #pragma unroll
        for (int m = 0; m < 3; ++m)
            #pragma unroll
            for (int n = 0; n < 2; ++n)
                #pragma unroll
                for (int jj = 0; jj < 4; ++jj) {
                    int row = m * 16 + q * 4 + jj;
                    int el = row / 3, i = row % 3;
                    SPSI[el * 304 + 64 + (n * 16 + r16) * 3 + i] = f2bb(dv[m][n][jj]);
                }
    } else {
        for (int mi = 0; mi < mcnt; ++mi)
            #pragma unroll
            for (int jj = 0; jj < 4; ++jj) {
                int row = (mstart + mi) * 16 + q * 4 + jj;
                int el = row / 9, ij = row % 9;
                SPSI[el * 304 + 160 + r16 * 9 + ij] = f2bb(dd[mi][jj]);
            }
    }
    __syncthreads();   // b3: psi_a + psi_v/d staged

    // ---- phase 3: fused MLP (M=16, waves split N)
    {
        f32x4 h1a[2] = {};
        #pragma unroll
        for (int ks = 0; ks < 2; ++ks) {
            bf16x8 af = *(const bf16x8*)&SPSIA[r16 * 72 + ks * 32 + q * 8];
            #pragma unroll
            for (int n = 0; n < 2; ++n) {
                int col = wid * 32 + n * 16 + r16;
                bf16x8 bf = *(const bf16x8*)((const short*)Wb1 + col * 64 + ks * 32 + q * 8);
                h1a[n] = __builtin_amdgcn_mfma_f32_16x16x32_bf16(af, bf, h1a[n], 0, 0, 0);
            }
        }
        #pragma unroll
        for (int n = 0; n < 2; ++n) {
            int col = wid * 32 + n * 16 + r16;
            float bias = b1[col];
            #pragma unroll
            for (int jj = 0; jj < 4; ++jj) {
                float v = h1a[n][jj] + bias;
                v = v >= 0.f ? v : 0.1f * v;
                SH1[(q * 4 + jj) * 136 + col] = f2bb(v);
            }
        }
    }
    __syncthreads();   // b4: h1 ready
    {
        f32x4 h2a[2] = {};
        #pragma unroll
        for (int ks = 0; ks < 4; ++ks) {
            bf16x8 af = *(const bf16x8*)&SH1[r16 * 136 + ks * 32 + q * 8];
            #pragma unroll
            for (int n = 0; n < 2; ++n) {
                int col = wid * 32 + n * 16 + r16;
                bf16x8 bf = *(const bf16x8*)((const short*)Wb2 + col * 128 + ks * 32 + q * 8);
                h2a[n] = __builtin_amdgcn_mfma_f32_16x16x32_bf16(af, bf, h2a[n], 0, 0, 0);
            }
        }
        #pragma unroll
        for (int n = 0; n < 2; ++n) {
            int col = wid * 32 + n * 16 + r16;
            float bias = b2[col];
            #pragma unroll
            for (int jj = 0; jj < 4; ++jj) {
                float v = h2a[n][jj] + bias;
                v = v >= 0.f ? v : 0.1f * v;
                SH2[(q * 4 + jj) * 136 + col] = f2bb(v);
            }
        }
    }
    __syncthreads();   // b5: h2 ready
    {
        f32x4 o3 = {};
        const int col3 = wid * 16 + r16;
        #pragma unroll
        for (int ks = 0; ks < 4; ++ks) {
            bf16x8 af = *(const bf16x8*)&SH2[r16 * 136 + ks * 32 + q * 8];
            bf16x8 bf = *(const bf16x8*)((const short*)Wb3 + col3 * 128 + ks * 32 + q * 8);
            o3 = __builtin_amdgcn_mfma_f32_16x16x32_bf16(af, bf, o3, 0, 0, 0);
        }
        #pragma unroll
        for (int ks = 0; ks < 2; ++ks) {
            bf16x8 af = *(const bf16x8*)&SPSIA[r16 * 72 + ks * 32 + q * 8];
            bf16x8 bf = *(const bf16x8*)((const short*)Wbdir + col3 * 64 + ks * 32 + q * 8);
            o3 = __builtin_amdgcn_mfma_f32_16x16x32_bf16(af, bf, o3, 0, 0, 0);
        }
        float bias = b3[col3];
        #pragma unroll
        for (int jj = 0; jj < 4; ++jj) {
            int row = q * 4 + jj;
            float v = o3[jj] + bias + bb2f(SPSIA[row * 72 + col3]);
            SPSI[row * 304 + col3] = f2bb(v);
        }
    }
    __syncthreads();   // b6: SPSI complete

    // ---- coalesced psi-row store at CSR slot
    {
        const uint32_t* S32 = (const uint32_t*)SPSI;
        uint32_t* P32 = (uint32_t*)psi;
        for (int idx = tid; idx < 16 * 152; idx += 256) {
            int le = idx / 152, k = idx - le * 152;
            if (e0 + le < E)
                P32[(size_t)SSLOT[le] * 152 + k] = S32[le * 152 + k];
        }
    }
}

// -------------------------------------------------------------- gather ----
__global__ __launch_bounds__(192) void gather(
    const short* __restrict__ psi, const int* __restrict__ rowstart,
    float* __restrict__ out, int N) {
    int n = blockIdx.x, t = threadIdx.x;
    if (t >= 152) return;
    int s0 = rowstart[n], s1 = rowstart[n + 1];
    const uint32_t* p32 = (const uint32_t*)psi;
    float a0 = 0.f, a1 = 0.f;
    for (int s = s0; s < s1; ++s) {
        uint32_t u = p32[(size_t)s * 152 + t];
        a0 += __uint_as_float(u << 16);
        a1 += __uint_as_float(u & 0xffff0000u);
    }
    int f = 2 * t;
    float2 v = make_float2(0.1f * a0, 0.1f * a1);
    if (f < 64)       *(float2*)&out[(size_t)n * 64 + f] = v;
    else if (f < 160) *(float2*)&out[(size_t)N * 64 + (size_t)n * 96 + (f - 64)] = v;
    else              *(float2*)&out[(size_t)N * 160 + (size_t)n * 144 + (f - 160)] = v;
}

// -------------------------------------------------------------- launch ----
extern "C" void kernel_launch(void* const* d_in, const int* in_sizes, int n_in,
                              void* d_out, int out_size, void* d_ws, size_t ws_size,
                              hipStream_t stream) {
    const float* r_ij = (const float*)d_in[0];
    const float* x_a  = (const float*)d_in[1];
    const float* x_v  = (const float*)d_in[2];
    const float* x_d  = (const float*)d_in[3];
    const float* W_L0 = (const float*)d_in[4];
    const float* W_L1 = (const float*)d_in[5];
    const float* W_L2 = (const float*)d_in[6];
    const float* W000 = (const float*)d_in[7];
    const float* W110 = (const float*)d_in[8];
    const float* W220 = (const float*)d_in[9];
    const float* W011 = (const float*)d_in[10];
    const float* W101 = (const float*)d_in[11];
    const float* W121 = (const float*)d_in[12];
    const float* W211 = (const float*)d_in[13];
    const float* W022 = (const float*)d_in[14];
    const float* W202 = (const float*)d_in[15];
    const float* W112 = (const float*)d_in[16];
    const float* W222 = (const float*)d_in[17];
    const float* W111 = (const float*)d_in[18];
    const float* W212 = (const float*)d_in[19];
    const float* Wenc = (const float*)d_in[20];
    const float* benc = (const float*)d_in[21];
    const float* Wdir = (const float*)d_in[22];
    const float* W1   = (const float*)d_in[23];
    const float* b1   = (const float*)d_in[24];
    const float* W2   = (const float*)d_in[25];
    const float* b2   = (const float*)d_in[26];
    const float* W3   = (const float*)d_in[27];
    const float* b3   = (const float*)d_in[28];
    const int* src    = (const int*)d_in[29];
    const int* dst    = (const int*)d_in[30];

    const int E = in_sizes[29];
    const int N = in_sizes[1] / 64;

    // ws layout
    float* Pa     = (float*)d_ws;                    // N*16
    float* Pv     = Pa + (size_t)N * 16;             // N*48
    float* Pd     = Pv + (size_t)N * 48;             // N*144
    bf16*  Wb     = (bf16*)(Pd + (size_t)N * 144);   // 45568 bf16
    int*   cnt    = (int*)(Wb + 45568);              // N
    int*   cursor = cnt + N;                         // N
    int*   rowst  = cursor + N;                      // N+1
    int*   slot   = rowst + N + 1;                   // E
    short* psi    = (short*)(slot + E);              // E*304 bf16

    const bf16* Wa_p    = Wb;
    const bf16* Wv_p    = Wb + 4096;
    const bf16* Wd_p    = Wb + 7168;
    const bf16* Wb1_p   = Wb + 8704;
    const bf16* Wb2_p   = Wb + 16896;
    const bf16* Wb3_p   = Wb + 33280;
    const bf16* Wbdir_p = Wb + 41472;

    zero_i32<<<80, 256, 0, stream>>>(cnt, 2 * N);    // cnt + cursor
    prep_w<<<178, 256, 0, stream>>>(W000, W110, W220, W011, W101, W121, W211, W111,
                                    W022, W202, W112, W222, W212, W1, W2, W3, Wdir, Wb);
    node_proj4<<<(N + 3) / 4, 256, 0, stream>>>(x_a, x_v, x_d, W_L0, W_L1, W_L2,
                                                Pa, Pv, Pd, N);
    hist_src<<<(E + 255) / 256, 256, 0, stream>>>(src, cnt, E);
    scan_rows<<<1, 256, 0, stream>>>(cnt, rowst, N);
    fill_slot<<<(E + 255) / 256, 256, 0, stream>>>(src, rowst, cursor, slot, E);
    edge_mfma<<<(E + 15) / 16, 256, 0, stream>>>(
        r_ij, Pa, Pv, Pd, Wenc, benc,
        Wa_p, Wv_p, Wd_p, Wb1_p, Wb2_p, Wb3_p, Wbdir_p,
        b1, b2, b3, slot, dst, psi, E);
    gather<<<N, 192, 0, stream>>>(psi, rowst, (float*)d_out, N);
}

// Round 8
// 242.063 us; speedup vs baseline: 12.7107x; 1.0124x over previous
//
#include <hip/hip_runtime.h>
#include <hip/hip_bf16.h>

typedef __hip_bfloat16 bf16;
typedef __attribute__((ext_vector_type(8))) short bf16x8;
typedef __attribute__((ext_vector_type(4))) float f32x4;

// cheap bf16 round+store: add 0x8000 (round-half-away), store high 16 bits.
// Compiler emits v_add_u32 + ds_write_b16_d16_hi (or global_store_short_d16_hi).
__device__ __forceinline__ void st_bf16(short* p, float v) {
    uint32_t u = __float_as_uint(v) + 0x8000u;
    *p = (short)(u >> 16);
}
__device__ __forceinline__ float bb2f(short s) {
    uint32_t u = ((uint32_t)(uint16_t)s) << 16;
    return __uint_as_float(u);
}

// ---------------------------------------------------------------- zero ----
__global__ void zero_i32(int* p, int n) {
    int i = blockIdx.x * blockDim.x + threadIdx.x;
    int stride = gridDim.x * blockDim.x;
    for (; i < n; i += stride) p[i] = 0;
}

// ------------------------------------------------------------- prep_all ----
// blockIdx ranges: [0,178) prep_w | [178, 178+NPB) node_proj (padded P out)
//                  | rest: hist of src
__global__ __launch_bounds__(256) void prep_all(
    const float* __restrict__ W000, const float* __restrict__ W110, const float* __restrict__ W220,
    const float* __restrict__ W011, const float* __restrict__ W101, const float* __restrict__ W121,
    const float* __restrict__ W211, const float* __restrict__ W111,
    const float* __restrict__ W022, const float* __restrict__ W202, const float* __restrict__ W112,
    const float* __restrict__ W222, const float* __restrict__ W212,
    const float* __restrict__ W1, const float* __restrict__ W2, const float* __restrict__ W3,
    const float* __restrict__ Wdir, bf16* __restrict__ wout,
    const float* __restrict__ xa, const float* __restrict__ xv, const float* __restrict__ xd,
    const float* __restrict__ WL0, const float* __restrict__ WL1, const float* __restrict__ WL2,
    float* __restrict__ Pa, float* __restrict__ Pv, float* __restrict__ Pd, int N, int NPB,
    const int* __restrict__ src, int* __restrict__ cnt, int E)
{
    int b = blockIdx.x;
    const int tid = threadIdx.x;
    if (b < 178) {
        // ---- weight packing (bf16, K zero-padded)
        int i = b * 256 + tid;
        if (i >= 45568) return;
        float v = 0.f;
        if (i < 4096) {
            int o = i >> 6, k = i & 63;
            if (k < 48) {
                int t = k >> 4, c = k & 15;
                const float* W = (t == 0) ? W000 : (t == 1) ? W110 : W220;
                v = W[o * 16 + c];
            }
        } else if (i < 7168) {
            int r = i - 4096, ch = r / 96, k = r % 96;
            if (k < 80) {
                int t = k >> 4, c = k & 15;
                const float* W = (t == 0) ? W011 : (t == 1) ? W101 : (t == 2) ? W121 : (t == 3) ? W211 : W111;
                v = W[ch * 16 + c];
            }
        } else if (i < 8704) {
            int r = i - 7168, ch = r / 96, k = r % 96;
            if (k < 80) {
                int t = k >> 4, c = k & 15;
                const float* W = (t == 0) ? W022 : (t == 1) ? W202 : (t == 2) ? W112 : (t == 3) ? W222 : W212;
                v = W[ch * 16 + c];
            }
        } else if (i < 16896) v = W1[i - 8704];
        else if (i < 33280) v = W2[i - 16896];
        else if (i < 41472) v = W3[i - 33280];
        else v = Wdir[i - 41472];
        wout[i] = __float2bfloat16(v);
        return;
    }
    b -= 178;
    if (b < NPB) {
        // ---- node projection, 4 nodes/block, padded output layouts
        __shared__ float sxa[256], sxv[384], sxd[576];
        const int n0 = b * 4;
        if (n0 + tid / 64 < N) sxa[tid] = xa[(size_t)n0 * 64 + tid];
        for (int i = tid; i < 384; i += 256) if (n0 + i / 96 < N)  sxv[i] = xv[(size_t)n0 * 96 + i];
        for (int i = tid; i < 576; i += 256) if (n0 + i / 144 < N) sxd[i] = xd[(size_t)n0 * 144 + i];
        __syncthreads();
        for (int o = tid; o < 832; o += 256) {
            int ln = o / 208, s = o % 208;
            int n = n0 + ln;
            if (n >= N) continue;
            if (s < 16) {
                float a = 0.f;
                const float* w = WL0 + s * 64;
                const float* x = sxa + ln * 64;
                for (int d = 0; d < 64; ++d) a += w[d] * x[d];
                Pa[(size_t)n * 16 + s] = a;
            } else if (s < 64) {
                int idx = s - 16, c = idx / 3, i = idx % 3;
                float a = 0.f;
                const float* w = WL1 + c * 32;
                const float* x = sxv + ln * 96;
                for (int d = 0; d < 32; ++d) a += w[d] * x[d * 3 + i];
                Pv[(size_t)n * 64 + c * 4 + i] = a;
            } else {
                int idx = s - 64, c = idx / 9, ij = idx % 9;
                float a = 0.f;
                const float* w = WL2 + c * 16;
                const float* x = sxd + ln * 144;
                for (int d = 0; d < 16; ++d) a += w[d] * x[d * 9 + ij];
                Pd[(size_t)n * 192 + c * 12 + ij] = a;
            }
        }
        return;
    }
    b -= NPB;
    // ---- histogram of src
    int i = b * 256 + tid;
    if (i < E) atomicAdd(&cnt[src[i]], 1);
}

// --------------------------------------------------------------- CSR ----
__global__ void scan_rows(const int* __restrict__ cnt, int* __restrict__ rowstart, int N) {
    __shared__ int ps[256];
    int t = threadIdx.x;
    int chunk = (N + 255) / 256;
    int base = t * chunk;
    int s = 0;
    for (int i = 0; i < chunk; ++i) { int idx = base + i; if (idx < N) s += cnt[idx]; }
    ps[t] = s;
    __syncthreads();
    for (int off = 1; off < 256; off <<= 1) {
        int v = (t >= off) ? ps[t - off] : 0;
        __syncthreads();
        ps[t] += v;
        __syncthreads();
    }
    int run = (t > 0) ? ps[t - 1] : 0;
    for (int i = 0; i < chunk; ++i) {
        int idx = base + i;
        if (idx < N) { rowstart[idx] = run; run += cnt[idx]; }
    }
    if (t == 255) rowstart[N] = run;
}

__global__ void fill_slot(const int* __restrict__ src, const int* __restrict__ rowstart,
                          int* __restrict__ cursor, int* __restrict__ slot, int E) {
    int i = blockIdx.x * 256 + threadIdx.x;
    if (i < E) slot[i] = rowstart[src[i]] + atomicAdd(&cursor[src[i]], 1);
}

// ---------------------------------------------------------- edge_mfma ----
// 16 edges/block, ~32.3KB LDS. Phase1 y-build with vectorized padded P loads
// and cheap bf16 stores; phase2 MFMA tensor GEMMs; phase3 fused MLP.
__global__ __launch_bounds__(256) void edge_mfma(
    const float* __restrict__ r_ij,
    const float* __restrict__ Pa, const float* __restrict__ Pv, const float* __restrict__ Pd,
    const float* __restrict__ Wenc, const float* __restrict__ benc,
    const bf16* __restrict__ Wa, const bf16* __restrict__ Wv, const bf16* __restrict__ Wd,
    const bf16* __restrict__ Wb1, const bf16* __restrict__ Wb2,
    const bf16* __restrict__ Wb3, const bf16* __restrict__ Wbdir,
    const float* __restrict__ b1, const float* __restrict__ b2, const float* __restrict__ b3,
    const int* __restrict__ slot, const int* __restrict__ dst,
    short* __restrict__ psi, int E)
{
    __shared__ __align__(16) char smem[32320];
    short* SYA   = (short*)smem;            // [16][48]
    short* SYV   = (short*)(smem + 1536);   // [48][80]
    short* SYD   = (short*)(smem + 9216);   // [144][80]
    int*   SSLOT = (int*)(smem + 32256);    // [16]
    // phase-3 aliases (valid after b2)
    short* SPSIA = (short*)(smem + 1536);   // [16][72]
    short* SH1   = (short*)(smem + 3840);   // [16][136]
    short* SH2   = (short*)(smem + 8192);   // [16][136]
    short* SPSI  = (short*)(smem + 12544);  // [16][304]

    const int tid = threadIdx.x;
    const int e0 = blockIdx.x * 16;
    const bf16x8 z8 = {};

    // ---- phase 1: y-build. thread = (local edge le, channel c)
    {
        const int le = tid >> 4, c = tid & 15;
        const int e = e0 + le;
        if (e < E) {
            const int j = dst[e];
            if (c == 0) SSLOT[le] = slot[e];
            float vx = 7.f * r_ij[e * 3 + 0];
            float vy = 7.f * r_ij[e * 3 + 1];
            float vz = 7.f * r_ij[e * 3 + 2];
            float nn = sqrtf(vx * vx + vy * vy + vz * vz);
            // tanh(nn) = (1-e^{-2nn})/(1+e^{-2nn}); rcp is 1-instr approx
            float ex = __expf(-2.f * nn);
            float th = (1.f - ex) * __builtin_amdgcn_rcpf(1.f + ex);
            float sc = th * __builtin_amdgcn_rcpf(nn + 1e-12f);
            float rr[3] = {vx * sc, vy * sc, vz * sc};
            float x8 = nn * (8.f / 7.f);
            float rad = benc[c];
            #pragma unroll
            for (int m = 0; m < 8; ++m) {
                float tt = x8 - (float)m;
                rad += __expf(-0.5f * tt * tt) * Wenc[c * 8 + m];
            }
            // padded vectorized P loads
            float xa = Pa[j * 16 + c];
            f32x4 pv4 = *(const f32x4*)(Pv + (size_t)j * 64 + c * 4);
            f32x4 pd0 = *(const f32x4*)(Pd + (size_t)j * 192 + c * 12);
            f32x4 pd1 = *(const f32x4*)(Pd + (size_t)j * 192 + c * 12 + 4);
            f32x4 pd2 = *(const f32x4*)(Pd + (size_t)j * 192 + c * 12 + 8);
            float xv[3] = {pv4[0], pv4[1], pv4[2]};
            float xd[9] = {pd0[0], pd0[1], pd0[2], pd0[3], pd1[0], pd1[1], pd1[2], pd1[3], pd2[0]};
            float dotv = xv[0] * rr[0] + xv[1] * rr[1] + xv[2] * rr[2];
            float mv[3];
            #pragma unroll
            for (int i = 0; i < 3; ++i)
                mv[i] = xd[i * 3] * rr[0] + xd[i * 3 + 1] * rr[1] + xd[i * 3 + 2] * rr[2];
            float quad = mv[0] * rr[0] + mv[1] * rr[1] + mv[2] * rr[2];
            st_bf16(&SYA[le * 48 + c],      xa * rad);
            st_bf16(&SYA[le * 48 + 16 + c], rad * dotv);
            st_bf16(&SYA[le * 48 + 32 + c], rad * quad);
            #pragma unroll
            for (int i = 0; i < 3; ++i) {
                int row = (le * 3 + i) * 80;
                int i1 = (i + 1) % 3, i2 = (i + 2) % 3;
                st_bf16(&SYV[row + c],      xa * rad * rr[i]);
                st_bf16(&SYV[row + 16 + c], rad * xv[i]);
                st_bf16(&SYV[row + 32 + c], rad * dotv * rr[i]);
                st_bf16(&SYV[row + 48 + c], rad * mv[i]);
                st_bf16(&SYV[row + 64 + c], rad * (xv[i1] * rr[i2] - xv[i2] * rr[i1]));
            }
            #pragma unroll
            for (int i = 0; i < 3; ++i) {
                int i1 = (i + 1) % 3, i2 = (i + 2) % 3;
                #pragma unroll
                for (int jj = 0; jj < 3; ++jj) {
                    int row = (le * 9 + i * 3 + jj) * 80;
                    st_bf16(&SYD[row + c],      xa * rad * rr[i] * rr[jj]);
                    st_bf16(&SYD[row + 16 + c], rad * xd[i * 3 + jj]);
                    st_bf16(&SYD[row + 32 + c], rad * xv[i] * rr[jj]);
                    st_bf16(&SYD[row + 48 + c], rad * mv[i] * rr[jj]);
                    st_bf16(&SYD[row + 64 + c], rad * (xd[i1 * 3 + jj] * rr[i2] - xd[i2 * 3 + jj] * rr[i1]));
                }
            }
        }
    }
    __syncthreads();   // b1: y ready

    // ---- phase 2: tensor GEMMs (accumulators persist across b2)
    const int wid = tid >> 6, lane = tid & 63;
    const int q = lane >> 4, r16 = lane & 15;

    f32x4 da[4] = {};
    f32x4 dv[3][2] = {};
    f32x4 dd[5] = {};
    const int mstart = (wid == 2) ? 0 : 5;
    const int mcnt = (wid == 2) ? 5 : 4;

    if (wid == 0) {
        bf16x8 af0 = *(const bf16x8*)&SYA[r16 * 48 + q * 8];
        bf16x8 af1 = z8;
        if (q < 2) af1 = *(const bf16x8*)&SYA[r16 * 48 + 32 + q * 8];
        #pragma unroll
        for (int n = 0; n < 4; ++n) {
            bf16x8 bf0 = *(const bf16x8*)((const short*)Wa + (n * 16 + r16) * 64 + q * 8);
            bf16x8 bf1 = *(const bf16x8*)((const short*)Wa + (n * 16 + r16) * 64 + 32 + q * 8);
            da[n] = __builtin_amdgcn_mfma_f32_16x16x32_bf16(af0, bf0, da[n], 0, 0, 0);
            da[n] = __builtin_amdgcn_mfma_f32_16x16x32_bf16(af1, bf1, da[n], 0, 0, 0);
        }
    } else if (wid == 1) {
        #pragma unroll
        for (int ks = 0; ks < 3; ++ks) {
            bf16x8 av[3], bv[2];
            #pragma unroll
            for (int m = 0; m < 3; ++m) {
                if (ks < 2) av[m] = *(const bf16x8*)&SYV[(m * 16 + r16) * 80 + ks * 32 + q * 8];
                else {
                    av[m] = z8;
                    if (q < 2) av[m] = *(const bf16x8*)&SYV[(m * 16 + r16) * 80 + 64 + q * 8];
                }
            }
            #pragma unroll
            for (int n = 0; n < 2; ++n)
                bv[n] = *(const bf16x8*)((const short*)Wv + (n * 16 + r16) * 96 + ks * 32 + q * 8);
            #pragma unroll
            for (int m = 0; m < 3; ++m)
                #pragma unroll
                for (int n = 0; n < 2; ++n)
                    dv[m][n] = __builtin_amdgcn_mfma_f32_16x16x32_bf16(av[m], bv[n], dv[m][n], 0, 0, 0);
        }
    } else {
        #pragma unroll
        for (int ks = 0; ks < 3; ++ks) {
            bf16x8 bf = *(const bf16x8*)((const short*)Wd + r16 * 96 + ks * 32 + q * 8);
            for (int mi = 0; mi < mcnt; ++mi) {
                bf16x8 af;
                if (ks < 2) af = *(const bf16x8*)&SYD[((mstart + mi) * 16 + r16) * 80 + ks * 32 + q * 8];
                else {
                    af = z8;
                    if (q < 2) af = *(const bf16x8*)&SYD[((mstart + mi) * 16 + r16) * 80 + 64 + q * 8];
                }
                dd[mi] = __builtin_amdgcn_mfma_f32_16x16x32_bf16(af, bf, dd[mi], 0, 0, 0);
            }
        }
    }
    __syncthreads();   // b2: all y reads done, alias region reusable

    // ---- epilogues into aliased region
    if (wid == 0) {
        #pragma unroll
        for (int n = 0; n < 4; ++n)
            #pragma unroll
            for (int jj = 0; jj < 4; ++jj)
                st_bf16(&SPSIA[(q * 4 + jj) * 72 + n * 16 + r16], da[n][jj]);
    } else if (wid == 1) {
        #pragma unroll
        for (int m = 0; m < 3; ++m)
            #pragma unroll
            for (int n = 0; n < 2; ++n)
                #pragma unroll
                for (int jj = 0; jj < 4; ++jj) {
                    int row = m * 16 + q * 4 + jj;
                    int el = row / 3, i = row % 3;
                    st_bf16(&SPSI[el * 304 + 64 + (n * 16 + r16) * 3 + i], dv[m][n][jj]);
                }
    } else {
        for (int mi = 0; mi < mcnt; ++mi)
            #pragma unroll
            for (int jj = 0; jj < 4; ++jj) {
                int row = (mstart + mi) * 16 + q * 4 + jj;
                int el = row / 9, ij = row % 9;
                st_bf16(&SPSI[el * 304 + 160 + r16 * 9 + ij], dd[mi][jj]);
            }
    }
    __syncthreads();   // b3: psi_a + psi_v/d staged

    // ---- phase 3: fused MLP (M=16, waves split N)
    {
        f32x4 h1a[2] = {};
        #pragma unroll
        for (int ks = 0; ks < 2; ++ks) {
            bf16x8 af = *(const bf16x8*)&SPSIA[r16 * 72 + ks * 32 + q * 8];
            #pragma unroll
            for (int n = 0; n < 2; ++n) {
                int col = wid * 32 + n * 16 + r16;
                bf16x8 bf = *(const bf16x8*)((const short*)Wb1 + col * 64 + ks * 32 + q * 8);
                h1a[n] = __builtin_amdgcn_mfma_f32_16x16x32_bf16(af, bf, h1a[n], 0, 0, 0);
            }
        }
        #pragma unroll
        for (int n = 0; n < 2; ++n) {
            int col = wid * 32 + n * 16 + r16;
            float bias = b1[col];
            #pragma unroll
            for (int jj = 0; jj < 4; ++jj) {
                float v = h1a[n][jj] + bias;
                v = v >= 0.f ? v : 0.1f * v;
                st_bf16(&SH1[(q * 4 + jj) * 136 + col], v);
            }
        }
    }
    __syncthreads();   // b4: h1 ready
    {
        f32x4 h2a[2] = {};
        #pragma unroll
        for (int ks = 0; ks < 4; ++ks) {
            bf16x8 af = *(const bf16x8*)&SH1[r16 * 136 + ks * 32 + q * 8];
            #pragma unroll
            for (int n = 0; n < 2; ++n) {
                int col = wid * 32 + n * 16 + r16;
                bf16x8 bf = *(const bf16x8*)((const short*)Wb2 + col * 128 + ks * 32 + q * 8);
                h2a[n] = __builtin_amdgcn_mfma_f32_16x16x32_bf16(af, bf, h2a[n], 0, 0, 0);
            }
        }
        #pragma unroll
        for (int n = 0; n < 2; ++n) {
            int col = wid * 32 + n * 16 + r16;
            float bias = b2[col];
            #pragma unroll
            for (int jj = 0; jj < 4; ++jj) {
                float v = h2a[n][jj] + bias;
                v = v >= 0.f ? v : 0.1f * v;
                st_bf16(&SH2[(q * 4 + jj) * 136 + col], v);
            }
        }
    }
    __syncthreads();   // b5: h2 ready
    {
        f32x4 o3 = {};
        const int col3 = wid * 16 + r16;
        #pragma unroll
        for (int ks = 0; ks < 4; ++ks) {
            bf16x8 af = *(const bf16x8*)&SH2[r16 * 136 + ks * 32 + q * 8];
            bf16x8 bf = *(const bf16x8*)((const short*)Wb3 + col3 * 128 + ks * 32 + q * 8);
            o3 = __builtin_amdgcn_mfma_f32_16x16x32_bf16(af, bf, o3, 0, 0, 0);
        }
        #pragma unroll
        for (int ks = 0; ks < 2; ++ks) {
            bf16x8 af = *(const bf16x8*)&SPSIA[r16 * 72 + ks * 32 + q * 8];
            bf16x8 bf = *(const bf16x8*)((const short*)Wbdir + col3 * 64 + ks * 32 + q * 8);
            o3 = __builtin_amdgcn_mfma_f32_16x16x32_bf16(af, bf, o3, 0, 0, 0);
        }
        float bias = b3[col3];
        #pragma unroll
        for (int jj = 0; jj < 4; ++jj) {
            int row = q * 4 + jj;
            float v = o3[jj] + bias + bb2f(SPSIA[row * 72 + col3]);
            st_bf16(&SPSI[row * 304 + col3], v);
        }
    }
    __syncthreads();   // b6: SPSI complete

    // ---- coalesced psi-row store at CSR slot
    {
        const uint32_t* S32 = (const uint32_t*)SPSI;
        uint32_t* P32 = (uint32_t*)psi;
        for (int idx = tid; idx < 16 * 152; idx += 256) {
            int le = idx / 152, k = idx - le * 152;
            if (e0 + le < E)
                P32[(size_t)SSLOT[le] * 152 + k] = S32[le * 152 + k];
        }
    }
}

// -------------------------------------------------------------- gather ----
__global__ __launch_bounds__(192) void gather(
    const short* __restrict__ psi, const int* __restrict__ rowstart,
    float* __restrict__ out, int N) {
    int n = blockIdx.x, t = threadIdx.x;
    if (t >= 152) return;
    int s0 = rowstart[n], s1 = rowstart[n + 1];
    const uint32_t* p32 = (const uint32_t*)psi;
    float a0 = 0.f, a1 = 0.f;
    for (int s = s0; s < s1; ++s) {
        uint32_t u = p32[(size_t)s * 152 + t];
        a0 += __uint_as_float(u << 16);
        a1 += __uint_as_float(u & 0xffff0000u);
    }
    int f = 2 * t;
    float2 v = make_float2(0.1f * a0, 0.1f * a1);
    if (f < 64)       *(float2*)&out[(size_t)n * 64 + f] = v;
    else if (f < 160) *(float2*)&out[(size_t)N * 64 + (size_t)n * 96 + (f - 64)] = v;
    else              *(float2*)&out[(size_t)N * 160 + (size_t)n * 144 + (f - 160)] = v;
}

// -------------------------------------------------------------- launch ----
extern "C" void kernel_launch(void* const* d_in, const int* in_sizes, int n_in,
                              void* d_out, int out_size, void* d_ws, size_t ws_size,
                              hipStream_t stream) {
    const float* r_ij = (const float*)d_in[0];
    const float* x_a  = (const float*)d_in[1];
    const float* x_v  = (const float*)d_in[2];
    const float* x_d  = (const float*)d_in[3];
    const float* W_L0 = (const float*)d_in[4];
    const float* W_L1 = (const float*)d_in[5];
    const float* W_L2 = (const float*)d_in[6];
    const float* W000 = (const float*)d_in[7];
    const float* W110 = (const float*)d_in[8];
    const float* W220 = (const float*)d_in[9];
    const float* W011 = (const float*)d_in[10];
    const float* W101 = (const float*)d_in[11];
    const float* W121 = (const float*)d_in[12];
    const float* W211 = (const float*)d_in[13];
    const float* W022 = (const float*)d_in[14];
    const float* W202 = (const float*)d_in[15];
    const float* W112 = (const float*)d_in[16];
    const float* W222 = (const float*)d_in[17];
    const float* W111 = (const float*)d_in[18];
    const float* W212 = (const float*)d_in[19];
    const float* Wenc = (const float*)d_in[20];
    const float* benc = (const float*)d_in[21];
    const float* Wdir = (const float*)d_in[22];
    const float* W1   = (const float*)d_in[23];
    const float* b1   = (const float*)d_in[24];
    const float* W2   = (const float*)d_in[25];
    const float* b2   = (const float*)d_in[26];
    const float* W3   = (const float*)d_in[27];
    const float* b3   = (const float*)d_in[28];
    const int* src    = (const int*)d_in[29];
    const int* dst    = (const int*)d_in[30];

    const int E = in_sizes[29];
    const int N = in_sizes[1] / 64;

    // ws layout (padded P)
    float* Pa     = (float*)d_ws;                    // N*16
    float* Pv     = Pa + (size_t)N * 16;             // N*64 (stride-4 pad)
    float* Pd     = Pv + (size_t)N * 64;             // N*192 (stride-12 pad)
    bf16*  Wb     = (bf16*)(Pd + (size_t)N * 192);   // 45568 bf16
    int*   cnt    = (int*)(Wb + 45568);              // N
    int*   cursor = cnt + N;                         // N
    int*   rowst  = cursor + N;                      // N+1
    int*   slot   = rowst + N + 1;                   // E
    short* psi    = (short*)(slot + E);              // E*304 bf16

    const bf16* Wa_p    = Wb;
    const bf16* Wv_p    = Wb + 4096;
    const bf16* Wd_p    = Wb + 7168;
    const bf16* Wb1_p   = Wb + 8704;
    const bf16* Wb2_p   = Wb + 16896;
    const bf16* Wb3_p   = Wb + 33280;
    const bf16* Wbdir_p = Wb + 41472;

    const int NPB = (N + 3) / 4;
    const int HB  = (E + 255) / 256;

    zero_i32<<<80, 256, 0, stream>>>(cnt, 2 * N);    // cnt + cursor
    prep_all<<<178 + NPB + HB, 256, 0, stream>>>(
        W000, W110, W220, W011, W101, W121, W211, W111,
        W022, W202, W112, W222, W212, W1, W2, W3, Wdir, Wb,
        x_a, x_v, x_d, W_L0, W_L1, W_L2, Pa, Pv, Pd, N, NPB,
        src, cnt, E);
    scan_rows<<<1, 256, 0, stream>>>(cnt, rowst, N);
    fill_slot<<<HB, 256, 0, stream>>>(src, rowst, cursor, slot, E);
    edge_mfma<<<(E + 15) / 16, 256, 0, stream>>>(
        r_ij, Pa, Pv, Pd, Wenc, benc,
        Wa_p, Wv_p, Wd_p, Wb1_p, Wb2_p, Wb3_p, Wbdir_p,
        b1, b2, b3, slot, dst, psi, E);
    gather<<<N, 192, 0, stream>>>(psi, rowst, (float*)d_out, N);
}